// Round 10
// baseline (475.795 us; speedup 1.0000x reference)
//
#include <hip/hip_runtime.h>
#include <hip/hip_bf16.h>
#include <math.h>

// ---------------------------------------------------------------------------
// GNNReranker: 4-layer GCN on MI355X.
// Intermediates stored as SEPARATE bf16 hi/lo planes (~f32 accuracy, 4 B/elem
// total) + fp8-e4m3 plane for neighbor gathers. K=128 GEMMs are LDS-FREE:
// MFMA fragments load directly from the hi/lo planes (16 B contiguous per
// lane). Input GEMM (f32 x, K=256) keeps LDS staging w/ split8, 64-row tiles.
// Edge weights fully pre-finalized (w15 = dinv_s*dinv_d*ewn*2^24) so the
// gather hot loop is: cv load -> fp8 load -> cvt -> 1 mul + 2 fma.
// Graph build: two-phase binning, no random-line HBM scatters.
// ---------------------------------------------------------------------------

#define CAP 64                 // padded CSR row capacity (mean deg 16)
#define BN 256                 // nodes per bucket
#define BCAP 5120              // bucket edge capacity (mean 4096, +16 sd)
#define CHUNK 4096             // edges per bin block
#define SRC_MASK 0x1FFFFu
#define Q_SCALE 16777216.0f    // 2^24
#define Q_INV   5.9604644775390625e-8f   // 2^-24

typedef __attribute__((ext_vector_type(8))) short bf16x8;
typedef __attribute__((ext_vector_type(2))) float f32x2;
typedef __attribute__((ext_vector_type(4))) float f32x4;
typedef __attribute__((ext_vector_type(4))) unsigned int u32x4;

// fp8x2 -> f32x2 decode: HW instruction if available, else bit-ops (value
// scaled by 2^-120, compensated via DEC_SCALE folded into the edge weight).
#if __has_builtin(__builtin_amdgcn_cvt_pk_f32_fp8)
#define DEC_SCALE 5.9604644775390625e-8f   // 2^-24
__device__ __forceinline__ f32x2 dec2(unsigned short t) {
  return __builtin_amdgcn_cvt_pk_f32_fp8((int)(unsigned)t, false);
}
#else
#define DEC_SCALE 7.922816251426434e28f    // 2^96 = 2^-24 * 2^120
__device__ __forceinline__ f32x2 dec2(unsigned short t) {
  f32x2 r;
  r.x = __builtin_bit_cast(float, (((unsigned)t & 0x80u) << 24) | (((unsigned)t & 0x7Fu) << 20));
  r.y = __builtin_bit_cast(float, (((unsigned)t & 0x8000u) << 16) | (((unsigned)t & 0x7F00u) << 12));
  return r;
}
#endif

__device__ __forceinline__ unsigned rne_bf16(float f) {
  const unsigned u = __builtin_bit_cast(unsigned, f);
  return (u + 0x7FFFu + ((u >> 16) & 1u)) >> 16;
}
__device__ __forceinline__ void split8(const f32x4 a, const f32x4 b,
                                       bf16x8& hi, bf16x8& lo) {
#pragma unroll
  for (int i = 0; i < 8; ++i) {
    const float f = (i < 4) ? a[i] : b[i - 4];
    const unsigned hb = rne_bf16(f);
    hi[i] = (short)hb;
    const float hf = __builtin_bit_cast(float, hb << 16);
    lo[i] = (short)rne_bf16(f - hf);
  }
}
// f32 -> OCP e4m3 byte (RNE; clamped)
__device__ __forceinline__ unsigned char enc_e4m3(float v) {
  const float a = v * 0x1p-120f;
  unsigned bits = __builtin_bit_cast(unsigned, a);
  const unsigned sgn = (bits >> 24) & 0x80u;
  bits &= 0x7FFFFFFFu;
  unsigned u7 = (bits + 0x7FFFFu + ((bits >> 20) & 1u)) >> 20;
  if (u7 > 0x7Eu) u7 = 0x7Eu;
  return (unsigned char)(sgn | u7);
}

// ---------------- edge weight + sum of squares (partial) -------------------
__global__ void ew_kernel(const float* __restrict__ ea, float* __restrict__ ew,
                          float* __restrict__ partial, int E) {
  __shared__ float red[256];
  const int tid = threadIdx.x;
  float ss = 0.f;
  const int stride = gridDim.x * blockDim.x;
  for (int e = blockIdx.x * blockDim.x + tid; e < E; e += stride) {
    const float4 a = *(const float4*)(ea + (size_t)e * 8);
    const float4 b = *(const float4*)(ea + (size_t)e * 8 + 4);
    const float s = ((a.x + a.y) + (a.z + a.w)) + ((b.x + b.y) + (b.z + b.w));
    ew[e] = s;
    ss = fmaf(s, s, ss);
  }
  red[tid] = ss;
  __syncthreads();
  for (int k = 128; k > 0; k >>= 1) {
    if (tid < k) red[tid] += red[tid + k];
    __syncthreads();
  }
  if (tid == 0) partial[blockIdx.x] = red[0];
}

__global__ void finish_norm_kernel(const float* __restrict__ partial,
                                   float* __restrict__ invnorm) {
  __shared__ float red[256];
  const int tid = threadIdx.x;
  float s = partial[tid] + partial[tid + 256] + partial[tid + 512] + partial[tid + 768];
  red[tid] = s;
  __syncthreads();
  for (int k = 128; k > 0; k >>= 1) {
    if (tid < k) red[tid] += red[tid + k];
    __syncthreads();
  }
  if (tid == 0) invnorm[0] = 1.0f / fmaxf(sqrtf(red[0]), 1e-12f);
}

// ---------------- pre-split ALL weights into bf16 hi/lo planes -------------
__global__ void wsplit_kernel(const float* __restrict__ W_in, const float* __restrict__ W1,
                              const float* __restrict__ W2, const float* __restrict__ W_out,
                              short* __restrict__ whi, short* __restrict__ wlo) {
  const int i = blockIdx.x * blockDim.x + threadIdx.x;
  if (i >= 81920) return;
  float f;
  if (i < 32768) f = W_in[i];
  else if (i < 49152) f = W1[i - 32768];
  else if (i < 65536) f = W2[i - 49152];
  else f = W_out[i - 65536];
  const unsigned hb = rne_bf16(f);
  whi[i] = (short)hb;
  wlo[i] = (short)rne_bf16(f - __builtin_bit_cast(float, hb << 16));
}

// ---------------- cursor init: one padded slot (64 B) per bucket -----------
__global__ void cursor_init_kernel(unsigned* __restrict__ cursors, int NB) {
  const int i = blockIdx.x * blockDim.x + threadIdx.x;
  if (i < NB) cursors[i * 16] = (unsigned)i * BCAP;
}

// ---------------- phase 1: bin edges by dst bucket -------------------------
__global__ __launch_bounds__(512) void bin_kernel(
    const int* __restrict__ src, const int* __restrict__ dst,
    const float* __restrict__ ew, const float* __restrict__ invnorm,
    unsigned* __restrict__ cursors, unsigned long long* __restrict__ buckets,
    int E, int NB) {
  __shared__ unsigned long long recs[CHUNK];   // 32 KB
  __shared__ unsigned hist[512];
  __shared__ unsigned base[512];
  const int tid = threadIdx.x;
  const int e0 = blockIdx.x * CHUNK;
  const int n = min(CHUNK, E - e0);
  for (int i = tid; i < NB; i += 512) hist[i] = 0;
  __syncthreads();
  const float inv = invnorm[0];
  for (int i = tid; i < n; i += 512) {
    const int s = src[e0 + i];
    const int d = dst[e0 + i];
    const float w = ew[e0 + i] * inv;
    const unsigned q = (unsigned)fminf(fmaf(w, Q_SCALE, 0.5f), 32767.0f);
    const unsigned long long r =
        ((unsigned long long)(((unsigned)d << 15) | q) << 32) | (unsigned)s;
    recs[i] = r;
    atomicAdd(&hist[d >> 8], 1u);
  }
  __syncthreads();
  for (int i = tid; i < NB; i += 512) {
    const unsigned c = hist[i];
    base[i] = c ? atomicAdd(&cursors[i * 16], c) : 0u;
    hist[i] = 0;
  }
  __syncthreads();
  for (int i = tid; i < n; i += 512) {
    const unsigned long long r = recs[i];
    const unsigned b = ((unsigned)(r >> 32) >> 15) >> 8;
    const unsigned pos = base[b] + atomicAdd(&hist[b], 1u);
    if (pos < (b + 1) * BCAP)
      __builtin_nontemporal_store(r, &buckets[pos]);
  }
}

// ---------------- phase 2: per-bucket LDS scatter + deg/dinv + stream ------
__global__ __launch_bounds__(256) void build_kernel(
    const unsigned long long* __restrict__ buckets,
    const unsigned* __restrict__ cursors,
    unsigned* __restrict__ cv, float* __restrict__ dinv,
    int* __restrict__ fillg, int N) {
  __shared__ unsigned cvl[BN * CAP];     // 64 KB
  __shared__ unsigned fl[BN];
  const int tid = threadIdx.x;
  const int b = blockIdx.x;
  const int n0 = b << 8;
  for (int i = tid; i < BN; i += 256) fl[i] = 0;
  __syncthreads();
  const unsigned start = (unsigned)b * BCAP;
  const int cnt = min((int)(cursors[b * 16] - start), BCAP);
  for (int i = tid; i < cnt; i += 256) {
    const unsigned long long r = buckets[start + i];
    const unsigned hi = (unsigned)(r >> 32);
    const unsigned dlo = (hi >> 15) & (BN - 1);
    const unsigned q = hi & 0x7FFFu;
    const unsigned p = atomicAdd(&fl[dlo], 1u);
    if (p < CAP) cvl[(dlo << 6) + p] = (q << 17) | (unsigned)(r & 0xFFFFFFFFu);
  }
  __syncthreads();
  if (n0 + tid < N) {
    const int c = min((int)fl[tid], CAP);
    unsigned qs = 0;
    for (int i = 0; i < c; ++i) qs += cvl[(tid << 6) + i] >> 17;
    dinv[n0 + tid] = rsqrtf(fmaf((float)qs, Q_INV, 1.0f));  // deg >= 1
    fillg[n0 + tid] = c;
  }
  const u32x4* s = (const u32x4*)cvl;
  u32x4* g = (u32x4*)(cv + ((size_t)b << 14));
  for (int i = tid; i < BN * CAP / 4; i += 256)
    __builtin_nontemporal_store(s[i], &g[i]);
}

// ---------------- finalize edge weights: q15 -> w15 ------------------------
__global__ void val_finalize_kernel(unsigned* __restrict__ cv, const int* __restrict__ fillg,
                                    const float* __restrict__ dinv, int N) {
  const int i = blockIdx.x * blockDim.x + threadIdx.x;
  if (i >= N * (CAP / 4)) return;
  const int n = i >> 4;
  const int slot0 = (i & 15) * 4;
  const int c = fillg[n];
  if (slot0 >= c) return;
  const float dn = dinv[n];
  u32x4 q = *(u32x4*)&cv[((size_t)n << 6) + slot0];
#pragma unroll
  for (int j = 0; j < 4; ++j) {
    if (slot0 + j < c) {
      const unsigned s = q[j] & SRC_MASK;
      const float wv = dinv[s] * dn * ((float)(q[j] >> 17) * Q_INV);
      const unsigned w15 = (unsigned)fminf(fmaf(wv, Q_SCALE, 0.5f), 32767.0f);
      q[j] = (w15 << 17) | s;
    }
  }
  *(u32x4*)&cv[((size_t)n << 6) + slot0] = q;
}

// ---------------- input GEMM: f32 x [N,256] -> relu(x@W^T+b) hi/lo ---------
// 64-row tiles, LDS-staged A (split8 once), swizzled planes, 8 waves.
__global__ __launch_bounds__(512) void gemm_in_kernel(
    const float* __restrict__ X, const short* __restrict__ Whi,
    const short* __restrict__ Wlo, const float* __restrict__ bias,
    unsigned short* __restrict__ Yhi, unsigned short* __restrict__ Ylo, int N) {
  constexpr int K = 256, KT = 8, RT = 4, CPR = 32;
  __shared__ short hi_p[64 * K];   // 32 KB
  __shared__ short lo_p[64 * K];   // 32 KB
  const int tid = threadIdx.x;
  const int lane = tid & 63, wave = tid >> 6;
  const int lrow = lane & 15, loct = lane >> 4;
  const int r0 = blockIdx.x * 64;

  bf16x8 bhi[KT], blo[KT];
  const int col = wave * 16 + lrow;
#pragma unroll
  for (int kt = 0; kt < KT; ++kt) {
    const int off = col * K + kt * 32 + loct * 8;
    bhi[kt] = *(const bf16x8*)&Whi[off];
    blo[kt] = *(const bf16x8*)&Wlo[off];
  }
  const float bv = bias[col];

#pragma unroll
  for (int s = tid; s < 64 * CPR; s += 512) {
    const int r = s / CPR, c = s % CPR;
    if (r0 + r < N) {
      const int slot = r * CPR + (c ^ (r & 7));
      const float* xp = X + (size_t)(r0 + r) * K + c * 8;
      bf16x8 h, l;
      split8(*(const f32x4*)xp, *(const f32x4*)(xp + 4), h, l);
      *(bf16x8*)&hi_p[slot * 8] = h;
      *(bf16x8*)&lo_p[slot * 8] = l;
    }
  }
  __syncthreads();

  f32x4 acc[RT];
#pragma unroll
  for (int rt = 0; rt < RT; ++rt) acc[rt] = f32x4{0.f, 0.f, 0.f, 0.f};

#pragma unroll
  for (int kt = 0; kt < KT; ++kt) {
    bf16x8 ahi[RT], alo[RT];
#pragma unroll
    for (int rt = 0; rt < RT; ++rt) {
      const int lr = rt * 16 + lrow;
      const int off = (lr * CPR + ((kt * 4 + loct) ^ (lr & 7))) * 8;
      ahi[rt] = *(const bf16x8*)&hi_p[off];
      alo[rt] = *(const bf16x8*)&lo_p[off];
    }
#pragma unroll
    for (int rt = 0; rt < RT; ++rt) {
      acc[rt] = __builtin_amdgcn_mfma_f32_16x16x32_bf16(ahi[rt], bhi[kt], acc[rt], 0, 0, 0);
      acc[rt] = __builtin_amdgcn_mfma_f32_16x16x32_bf16(ahi[rt], blo[kt], acc[rt], 0, 0, 0);
      acc[rt] = __builtin_amdgcn_mfma_f32_16x16x32_bf16(alo[rt], bhi[kt], acc[rt], 0, 0, 0);
    }
  }

#pragma unroll
  for (int rt = 0; rt < RT; ++rt)
#pragma unroll
    for (int r = 0; r < 4; ++r) {
      const int row = r0 + rt * 16 + loct * 4 + r;
      if (row < N) {
        const float v = fmaxf(acc[rt][r] + bv, 0.f);
        const unsigned hb = rne_bf16(v);
        const unsigned lb = rne_bf16(v - __builtin_bit_cast(float, hb << 16));
        const size_t idx = (size_t)row * 128 + col;
        Yhi[idx] = (unsigned short)hb;
        Ylo[idx] = (unsigned short)lb;
      }
    }
}

// ---------------- LDS-free K=128 GEMM: hi/lo planes in, planes/f32 out -----
// A/B fragments are DIRECT 16 B global loads (16 full lines per wave instr).
// No LDS, no barriers; latency hidden by 3 waves/SIMD + deep load queue.
template <bool OUT_FP8, bool OUT_F32, bool HAS_BIAS, bool RELU>
__global__ __launch_bounds__(256) void gemm_direct_kernel(
    const unsigned short* __restrict__ Xhi, const unsigned short* __restrict__ Xlo,
    const short* __restrict__ Whi, const short* __restrict__ Wlo,
    const float* __restrict__ bias,
    unsigned short* __restrict__ Yhi, unsigned short* __restrict__ Ylo,
    unsigned char* __restrict__ Yf8, float* __restrict__ Yf32) {
  constexpr int K = 128, KT = 4, CT = 2, RT = 2;
  const int lane = threadIdx.x & 63, wave = threadIdx.x >> 6;
  const int lrow = lane & 15, loct = lane >> 4;
  const int r0 = blockIdx.x * 32;

  bf16x8 ahi[RT][KT], alo[RT][KT];
#pragma unroll
  for (int rt = 0; rt < RT; ++rt) {
    const size_t ro = (size_t)(r0 + rt * 16 + lrow) * K + loct * 8;
#pragma unroll
    for (int kt = 0; kt < KT; ++kt) {
      ahi[rt][kt] = *(const bf16x8*)&Xhi[ro + kt * 32];
      alo[rt][kt] = *(const bf16x8*)&Xlo[ro + kt * 32];
    }
  }
  bf16x8 bhi[CT][KT], blo[CT][KT];
#pragma unroll
  for (int ct = 0; ct < CT; ++ct) {
    const int col = (wave * CT + ct) * 16 + lrow;
#pragma unroll
    for (int kt = 0; kt < KT; ++kt) {
      const int off = col * K + kt * 32 + loct * 8;
      bhi[ct][kt] = *(const bf16x8*)&Whi[off];
      blo[ct][kt] = *(const bf16x8*)&Wlo[off];
    }
  }

  f32x4 acc[RT][CT];
#pragma unroll
  for (int rt = 0; rt < RT; ++rt)
#pragma unroll
    for (int ct = 0; ct < CT; ++ct) acc[rt][ct] = f32x4{0.f, 0.f, 0.f, 0.f};

#pragma unroll
  for (int kt = 0; kt < KT; ++kt)
#pragma unroll
    for (int rt = 0; rt < RT; ++rt)
#pragma unroll
      for (int ct = 0; ct < CT; ++ct) {
        acc[rt][ct] = __builtin_amdgcn_mfma_f32_16x16x32_bf16(ahi[rt][kt], bhi[ct][kt], acc[rt][ct], 0, 0, 0);
        acc[rt][ct] = __builtin_amdgcn_mfma_f32_16x16x32_bf16(ahi[rt][kt], blo[ct][kt], acc[rt][ct], 0, 0, 0);
        acc[rt][ct] = __builtin_amdgcn_mfma_f32_16x16x32_bf16(alo[rt][kt], bhi[ct][kt], acc[rt][ct], 0, 0, 0);
      }

  float bv[CT];
  if constexpr (HAS_BIAS) {
#pragma unroll
    for (int ct = 0; ct < CT; ++ct) bv[ct] = bias[(wave * CT + ct) * 16 + lrow];
  }
#pragma unroll
  for (int rt = 0; rt < RT; ++rt)
#pragma unroll
    for (int ct = 0; ct < CT; ++ct) {
      const int col = (wave * CT + ct) * 16 + lrow;
#pragma unroll
      for (int r = 0; r < 4; ++r) {
        float v = acc[rt][ct][r];
        if constexpr (HAS_BIAS) v += bv[ct];
        if constexpr (RELU) v = fmaxf(v, 0.f);
        const size_t idx = (size_t)(r0 + rt * 16 + loct * 4 + r) * 128 + col;
        if constexpr (OUT_F32) {
          Yf32[idx] = v;
        } else {
          const unsigned hb = rne_bf16(v);
          const unsigned lb = rne_bf16(v - __builtin_bit_cast(float, hb << 16));
          Yhi[idx] = (unsigned short)hb;
          Ylo[idx] = (unsigned short)lb;
          if constexpr (OUT_FP8) Yf8[idx] = enc_e4m3(v);
        }
      }
    }
}

// ---------------- gather-aggregate: one wave/node, fp8 neighbors -----------
template <bool RELU>
__global__ __launch_bounds__(256) void gather_kernel(
    const unsigned short* __restrict__ Xhi, const unsigned short* __restrict__ Xlo,
    const unsigned char* __restrict__ xf8, const int* __restrict__ fill,
    const unsigned* __restrict__ cv, const float* __restrict__ dinv,
    const float* __restrict__ bias,
    unsigned short* __restrict__ Yhi, unsigned short* __restrict__ Ylo, int N) {
  const int lane = threadIdx.x & 63;
  const int n = (blockIdx.x * blockDim.x + threadIdx.x) >> 6;
  if (n >= N) return;
  const int f = lane * 2;
  const float dn = dinv[n];
  const float dn2 = dn * dn;
  const unsigned hx = *(const unsigned*)&Xhi[(size_t)n * 128 + f];
  const unsigned lx = *(const unsigned*)&Xlo[(size_t)n * 128 + f];
  float ax = dn2 * (__builtin_bit_cast(float, hx << 16) +
                    __builtin_bit_cast(float, lx << 16));
  float ay = dn2 * (__builtin_bit_cast(float, hx & 0xFFFF0000u) +
                    __builtin_bit_cast(float, lx & 0xFFFF0000u));
  const unsigned* row = cv + ((size_t)n << 6);
  const int c = min(fill[n], CAP);
  int e = 0;
  for (; e + 8 <= c; e += 8) {
    unsigned cr[8];
    unsigned short t[8];
#pragma unroll
    for (int j = 0; j < 8; ++j) cr[j] = row[e + j];
#pragma unroll
    for (int j = 0; j < 8; ++j)
      t[j] = *(const unsigned short*)&xf8[(size_t)(cr[j] & SRC_MASK) * 128 + f];
#pragma unroll
    for (int j = 0; j < 8; ++j) {
      const float vs = (float)(cr[j] >> 17) * DEC_SCALE;
      const f32x2 xy = dec2(t[j]);
      ax = fmaf(vs, xy.x, ax);
      ay = fmaf(vs, xy.y, ay);
    }
  }
  for (; e < c; ++e) {
    const unsigned cr = row[e];
    const float vs = (float)(cr >> 17) * DEC_SCALE;
    const f32x2 xy = dec2(*(const unsigned short*)&xf8[(size_t)(cr & SRC_MASK) * 128 + f]);
    ax = fmaf(vs, xy.x, ax);
    ay = fmaf(vs, xy.y, ay);
  }
  const float2 bb = *(const float2*)&bias[f];
  float o0 = ax + bb.x, o1 = ay + bb.y;
  if (RELU) { o0 = fmaxf(o0, 0.f); o1 = fmaxf(o1, 0.f); }
  const unsigned h0 = rne_bf16(o0), h1 = rne_bf16(o1);
  const unsigned l0 = rne_bf16(o0 - __builtin_bit_cast(float, h0 << 16));
  const unsigned l1 = rne_bf16(o1 - __builtin_bit_cast(float, h1 << 16));
  *(unsigned*)&Yhi[(size_t)n * 128 + f] = (h1 << 16) | h0;
  *(unsigned*)&Ylo[(size_t)n * 128 + f] = (l1 << 16) | l0;
}

// ---------------------------------------------------------------------------
extern "C" void kernel_launch(void* const* d_in, const int* in_sizes, int n_in,
                              void* d_out, int out_size, void* d_ws, size_t ws_size,
                              hipStream_t stream) {
  const float* x     = (const float*)d_in[0];
  const int*   eidx  = (const int*)d_in[1];
  const float* ea    = (const float*)d_in[2];
  const float* W_in  = (const float*)d_in[3];
  const float* b_in  = (const float*)d_in[4];
  const float* W1    = (const float*)d_in[5];
  const float* b1    = (const float*)d_in[6];
  const float* W2    = (const float*)d_in[7];
  const float* b2    = (const float*)d_in[8];
  const float* W_out = (const float*)d_in[9];
  const float* b_out = (const float*)d_in[10];

  const int E = in_sizes[2] / 8;          // edge_attr [E,8]
  const int N = in_sizes[0] / 256;        // x [N,256]
  const int* srcp = eidx;                 // edge_index [2,E] row-major
  const int* dstp = eidx + E;
  const int NB = (N + BN - 1) / BN;       // buckets

  char* w = (char*)d_ws;
  size_t o = 0;
  auto take = [&](size_t bytes) -> void* {
    void* p = w + o;
    o += (bytes + 255) & ~(size_t)255;
    return p;
  };
  float* ew            = (float*)take((size_t)E * 4);
  float* partial       = (float*)take(1024 * 4);
  float* invnorm       = (float*)take(256);
  float* dinv          = (float*)take((size_t)N * 4);
  int*   fillg         = (int*)take((size_t)N * 4);
  short* whi           = (short*)take(81920 * 2);
  short* wlo           = (short*)take(81920 * 2);
  unsigned* cursors    = (unsigned*)take((size_t)NB * 16 * 4);  // 64B-padded
  unsigned long long* buckets = (unsigned long long*)take((size_t)NB * BCAP * 8);
  unsigned* cv         = (unsigned*)take((size_t)NB * BN * CAP * 4);
  unsigned short* hi0  = (unsigned short*)take((size_t)N * 128 * 2);
  unsigned short* lo0  = (unsigned short*)take((size_t)N * 128 * 2);
  unsigned short* hi1  = (unsigned short*)take((size_t)N * 128 * 2);
  unsigned short* lo1  = (unsigned short*)take((size_t)N * 128 * 2);
  unsigned char* buff8 = (unsigned char*)take((size_t)N * 128);
  float* outp          = (float*)d_out;

  const int nt32 = N / 32;                // N % 32 == 0
  const int nt64 = (N + 63) / 64;

  // 1. edge weights + global L2 norm; pre-split weights
  ew_kernel<<<1024, 256, 0, stream>>>(ea, ew, partial, E);
  finish_norm_kernel<<<1, 256, 0, stream>>>(partial, invnorm);
  wsplit_kernel<<<320, 256, 0, stream>>>(W_in, W1, W2, W_out, whi, wlo);

  // 2. graph structure: bin -> per-bucket LDS build -> weight finalize
  cursor_init_kernel<<<(NB + 255) / 256, 256, 0, stream>>>(cursors, NB);
  bin_kernel<<<(E + CHUNK - 1) / CHUNK, 512, 0, stream>>>(srcp, dstp, ew, invnorm,
                                                          cursors, buckets, E, NB);
  build_kernel<<<NB, 256, 0, stream>>>(buckets, cursors, cv, dinv, fillg, N);
  val_finalize_kernel<<<(N * 16 + 255) / 256, 256, 0, stream>>>(cv, fillg, dinv, N);

  // 3. layer pipeline (hi/lo bf16 plane intermediates + fp8 neighbor plane)
  // h0 = relu(x @ W_in^T + b_in)                  -> hi0/lo0
  gemm_in_kernel<<<nt64, 512, 0, stream>>>(x, whi, wlo, b_in, hi0, lo0, N);
  // xw1 = h0 @ W1^T                               -> hi1/lo1 + buff8
  gemm_direct_kernel<true, false, false, false><<<nt32, 256, 0, stream>>>(
      hi0, lo0, whi + 32768, wlo + 32768, nullptr, hi1, lo1, buff8, nullptr);
  // s1 = relu(agg(xw1) + b1)                      -> hi0/lo0
  gather_kernel<true><<<(N * 64 + 255) / 256, 256, 0, stream>>>(
      hi1, lo1, buff8, fillg, cv, dinv, b1, hi0, lo0, N);
  // xw2 = s1 @ W2^T                               -> hi1/lo1 + buff8
  gemm_direct_kernel<true, false, false, false><<<nt32, 256, 0, stream>>>(
      hi0, lo0, whi + 49152, wlo + 49152, nullptr, hi1, lo1, buff8, nullptr);
  // s2 = agg(xw2) + b2                            -> hi0/lo0
  gather_kernel<false><<<(N * 64 + 255) / 256, 256, 0, stream>>>(
      hi1, lo1, buff8, fillg, cv, dinv, b2, hi0, lo0, N);
  // out = s2 @ W_out^T + b_out                    -> d_out (f32)
  gemm_direct_kernel<false, true, true, false><<<nt32, 256, 0, stream>>>(
      hi0, lo0, whi + 65536, wlo + 65536, b_out, nullptr, nullptr, nullptr, outp);
}

// Round 11
// 394.693 us; speedup vs baseline: 1.2055x; 1.2055x over previous
//
#include <hip/hip_runtime.h>
#include <hip/hip_bf16.h>
#include <math.h>

// ---------------------------------------------------------------------------
// GNNReranker: 4-layer GCN on MI355X.  (round-9 structure + pipelined gemm_in)
// Self-loop dominates the normalized adjacency (deg ~= 1.01):
//  - self term from pk (hi/lo bf16 pair, ~f32) stream,
//  - neighbor terms gathered from an fp8-e4m3 plane (1 B/feature).
// Edge weights FULLY pre-finalized into cv (w15 = dinv_s*dinv_d*ewn * 2^24),
// so the gather hot loop is: cr load -> fp8 row load -> cvt_pk_f32_fp8 ->
// 2 fma. GEMMs: bf16 MFMA, 3-product split accumulation, LDS-staged A;
// weights pre-split ONCE into bf16 hi/lo planes. Input GEMM is software-
// pipelined: persistent blocks, register-staged next-tile loads issued before
// the MFMA phase so HBM latency hides under compute.
// Graph build: two-phase binning, no random-line HBM scatters.
// ---------------------------------------------------------------------------

#define CAP 64                 // padded CSR row capacity (mean deg 16)
#define BN 256                 // nodes per bucket
#define BCAP 5120              // bucket edge capacity (mean 4096, +16 sd)
#define CHUNK 4096             // edges per bin block
#define SRC_MASK 0x1FFFFu
#define Q_SCALE 16777216.0f    // 2^24
#define Q_INV   5.9604644775390625e-8f   // 2^-24

typedef __attribute__((ext_vector_type(8))) short bf16x8;
typedef __attribute__((ext_vector_type(2))) float f32x2;
typedef __attribute__((ext_vector_type(4))) float f32x4;
typedef __attribute__((ext_vector_type(4))) unsigned int u32x4;

// fp8x2 -> f32x2 decode: HW instruction if available, else bit-ops (value
// scaled by 2^-120, compensated via DEC_SCALE folded into the edge weight).
#if __has_builtin(__builtin_amdgcn_cvt_pk_f32_fp8)
#define DEC_SCALE 5.9604644775390625e-8f   // 2^-24
__device__ __forceinline__ f32x2 dec2(unsigned short t) {
  return __builtin_amdgcn_cvt_pk_f32_fp8((int)(unsigned)t, false);
}
#else
#define DEC_SCALE 7.922816251426434e28f    // 2^96 = 2^-24 * 2^120
__device__ __forceinline__ f32x2 dec2(unsigned short t) {
  f32x2 r;
  r.x = __builtin_bit_cast(float, (((unsigned)t & 0x80u) << 24) | (((unsigned)t & 0x7Fu) << 20));
  r.y = __builtin_bit_cast(float, (((unsigned)t & 0x8000u) << 16) | (((unsigned)t & 0x7F00u) << 12));
  return r;
}
#endif

__device__ __forceinline__ unsigned rne_bf16(float f) {
  const unsigned u = __builtin_bit_cast(unsigned, f);
  return (u + 0x7FFFu + ((u >> 16) & 1u)) >> 16;
}
__device__ __forceinline__ unsigned packsplit(float f) {
  const unsigned hb = rne_bf16(f);
  const float hf = __builtin_bit_cast(float, hb << 16);
  const unsigned lb = rne_bf16(f - hf);
  return (hb << 16) | (lb & 0xFFFFu);
}
__device__ __forceinline__ float unpk(unsigned p) {
  return __builtin_bit_cast(float, p & 0xFFFF0000u) +
         __builtin_bit_cast(float, p << 16);
}
__device__ __forceinline__ void split8(const f32x4 a, const f32x4 b,
                                       bf16x8& hi, bf16x8& lo) {
#pragma unroll
  for (int i = 0; i < 8; ++i) {
    const float f = (i < 4) ? a[i] : b[i - 4];
    const unsigned hb = rne_bf16(f);
    hi[i] = (short)hb;
    const float hf = __builtin_bit_cast(float, hb << 16);
    lo[i] = (short)rne_bf16(f - hf);
  }
}
// f32 -> OCP e4m3 byte (RNE; clamped)
__device__ __forceinline__ unsigned char enc_e4m3(float v) {
  const float a = v * 0x1p-120f;
  unsigned bits = __builtin_bit_cast(unsigned, a);
  const unsigned sgn = (bits >> 24) & 0x80u;
  bits &= 0x7FFFFFFFu;
  unsigned u7 = (bits + 0x7FFFFu + ((bits >> 20) & 1u)) >> 20;
  if (u7 > 0x7Eu) u7 = 0x7Eu;
  return (unsigned char)(sgn | u7);
}

// ---------------- edge weight + sum of squares (partial) -------------------
__global__ void ew_kernel(const float* __restrict__ ea, float* __restrict__ ew,
                          float* __restrict__ partial, int E) {
  __shared__ float red[256];
  const int tid = threadIdx.x;
  float ss = 0.f;
  const int stride = gridDim.x * blockDim.x;
  for (int e = blockIdx.x * blockDim.x + tid; e < E; e += stride) {
    const float4 a = *(const float4*)(ea + (size_t)e * 8);
    const float4 b = *(const float4*)(ea + (size_t)e * 8 + 4);
    const float s = ((a.x + a.y) + (a.z + a.w)) + ((b.x + b.y) + (b.z + b.w));
    ew[e] = s;
    ss = fmaf(s, s, ss);
  }
  red[tid] = ss;
  __syncthreads();
  for (int k = 128; k > 0; k >>= 1) {
    if (tid < k) red[tid] += red[tid + k];
    __syncthreads();
  }
  if (tid == 0) partial[blockIdx.x] = red[0];
}

__global__ void finish_norm_kernel(const float* __restrict__ partial,
                                   float* __restrict__ invnorm) {
  __shared__ float red[256];
  const int tid = threadIdx.x;
  float s = partial[tid] + partial[tid + 256] + partial[tid + 512] + partial[tid + 768];
  red[tid] = s;
  __syncthreads();
  for (int k = 128; k > 0; k >>= 1) {
    if (tid < k) red[tid] += red[tid + k];
    __syncthreads();
  }
  if (tid == 0) invnorm[0] = 1.0f / fmaxf(sqrtf(red[0]), 1e-12f);
}

// ---------------- pre-split ALL weights into bf16 hi/lo planes -------------
__global__ void wsplit_kernel(const float* __restrict__ W_in, const float* __restrict__ W1,
                              const float* __restrict__ W2, const float* __restrict__ W_out,
                              short* __restrict__ whi, short* __restrict__ wlo) {
  const int i = blockIdx.x * blockDim.x + threadIdx.x;
  if (i >= 81920) return;
  float f;
  if (i < 32768) f = W_in[i];
  else if (i < 49152) f = W1[i - 32768];
  else if (i < 65536) f = W2[i - 49152];
  else f = W_out[i - 65536];
  const unsigned hb = rne_bf16(f);
  whi[i] = (short)hb;
  wlo[i] = (short)rne_bf16(f - __builtin_bit_cast(float, hb << 16));
}

// ---------------- cursor init: one padded slot (64 B) per bucket -----------
__global__ void cursor_init_kernel(unsigned* __restrict__ cursors, int NB) {
  const int i = blockIdx.x * blockDim.x + threadIdx.x;
  if (i < NB) cursors[i * 16] = (unsigned)i * BCAP;
}

// ---------------- phase 1: bin edges by dst bucket -------------------------
__global__ __launch_bounds__(512) void bin_kernel(
    const int* __restrict__ src, const int* __restrict__ dst,
    const float* __restrict__ ew, const float* __restrict__ invnorm,
    unsigned* __restrict__ cursors, unsigned long long* __restrict__ buckets,
    int E, int NB) {
  __shared__ unsigned long long recs[CHUNK];   // 32 KB
  __shared__ unsigned hist[512];
  __shared__ unsigned base[512];
  const int tid = threadIdx.x;
  const int e0 = blockIdx.x * CHUNK;
  const int n = min(CHUNK, E - e0);
  for (int i = tid; i < NB; i += 512) hist[i] = 0;
  __syncthreads();
  const float inv = invnorm[0];
  for (int i = tid; i < n; i += 512) {
    const int s = src[e0 + i];
    const int d = dst[e0 + i];
    const float w = ew[e0 + i] * inv;
    const unsigned q = (unsigned)fminf(fmaf(w, Q_SCALE, 0.5f), 32767.0f);
    const unsigned long long r =
        ((unsigned long long)(((unsigned)d << 15) | q) << 32) | (unsigned)s;
    recs[i] = r;
    atomicAdd(&hist[d >> 8], 1u);
  }
  __syncthreads();
  for (int i = tid; i < NB; i += 512) {
    const unsigned c = hist[i];
    base[i] = c ? atomicAdd(&cursors[i * 16], c) : 0u;
    hist[i] = 0;
  }
  __syncthreads();
  for (int i = tid; i < n; i += 512) {
    const unsigned long long r = recs[i];
    const unsigned b = ((unsigned)(r >> 32) >> 15) >> 8;
    const unsigned pos = base[b] + atomicAdd(&hist[b], 1u);
    if (pos < (b + 1) * BCAP)
      __builtin_nontemporal_store(r, &buckets[pos]);
  }
}

// ---------------- phase 2: per-bucket LDS scatter + deg/dinv + stream ------
__global__ __launch_bounds__(256) void build_kernel(
    const unsigned long long* __restrict__ buckets,
    const unsigned* __restrict__ cursors,
    unsigned* __restrict__ cv, float* __restrict__ dinv,
    int* __restrict__ fillg, int N) {
  __shared__ unsigned cvl[BN * CAP];     // 64 KB
  __shared__ unsigned fl[BN];
  const int tid = threadIdx.x;
  const int b = blockIdx.x;
  const int n0 = b << 8;
  for (int i = tid; i < BN; i += 256) fl[i] = 0;
  __syncthreads();
  const unsigned start = (unsigned)b * BCAP;
  const int cnt = min((int)(cursors[b * 16] - start), BCAP);
  for (int i = tid; i < cnt; i += 256) {
    const unsigned long long r = buckets[start + i];
    const unsigned hi = (unsigned)(r >> 32);
    const unsigned dlo = (hi >> 15) & (BN - 1);
    const unsigned q = hi & 0x7FFFu;
    const unsigned p = atomicAdd(&fl[dlo], 1u);
    if (p < CAP) cvl[(dlo << 6) + p] = (q << 17) | (unsigned)(r & 0xFFFFFFFFu);
  }
  __syncthreads();
  if (n0 + tid < N) {
    const int c = min((int)fl[tid], CAP);
    unsigned qs = 0;
    for (int i = 0; i < c; ++i) qs += cvl[(tid << 6) + i] >> 17;
    dinv[n0 + tid] = rsqrtf(fmaf((float)qs, Q_INV, 1.0f));  // deg >= 1
    fillg[n0 + tid] = c;
  }
  const u32x4* s = (const u32x4*)cvl;
  u32x4* g = (u32x4*)(cv + ((size_t)b << 14));
  for (int i = tid; i < BN * CAP / 4; i += 256)
    __builtin_nontemporal_store(s[i], &g[i]);
}

// ---------------- finalize edge weights: q15 -> w15 ------------------------
__global__ void val_finalize_kernel(unsigned* __restrict__ cv, const int* __restrict__ fillg,
                                    const float* __restrict__ dinv, int N) {
  const int i = blockIdx.x * blockDim.x + threadIdx.x;
  if (i >= N * (CAP / 4)) return;
  const int n = i >> 4;
  const int slot0 = (i & 15) * 4;
  const int c = fillg[n];
  if (slot0 >= c) return;
  const float dn = dinv[n];
  u32x4 q = *(u32x4*)&cv[((size_t)n << 6) + slot0];
#pragma unroll
  for (int j = 0; j < 4; ++j) {
    if (slot0 + j < c) {
      const unsigned s = q[j] & SRC_MASK;
      const float wv = dinv[s] * dn * ((float)(q[j] >> 17) * Q_INV);
      const unsigned w15 = (unsigned)fminf(fmaf(wv, Q_SCALE, 0.5f), 32767.0f);
      q[j] = (w15 << 17) | s;
    }
  }
  *(u32x4*)&cv[((size_t)n << 6) + slot0] = q;
}

// ---------------- pipelined input GEMM: f32 x[N,256] -> relu(x@W^T+b) pk ---
// Persistent blocks (grid 1024, ~3 tiles each). Register-carried pipeline:
// next tile's global loads are issued BEFORE the MFMA phase of the current
// tile, so HBM latency hides under ds_read+MFMA. Single 32 KB LDS buffer.
__global__ __launch_bounds__(512, 4) void gemm_in_pipe(
    const float* __restrict__ X, const short* __restrict__ Whi,
    const short* __restrict__ Wlo, const float* __restrict__ bias,
    unsigned* __restrict__ Ypk, int ntiles) {
  constexpr int K = 256, KT = 8, RT = 2, CPR = 32;
  __shared__ short hi_p[32 * K];   // 16 KB
  __shared__ short lo_p[32 * K];   // 16 KB
  const int tid = threadIdx.x;
  const int lane = tid & 63, wave = tid >> 6;
  const int lrow = lane & 15, loct = lane >> 4;

  // B fragments: wave owns coltile `wave` (8 waves x 16 cols = 128)
  bf16x8 bhi[KT], blo[KT];
  const int col = wave * 16 + lrow;
#pragma unroll
  for (int kt = 0; kt < KT; ++kt) {
    const int off = col * K + kt * 32 + loct * 8;
    bhi[kt] = *(const bf16x8*)&Whi[off];
    blo[kt] = *(const bf16x8*)&Wlo[off];
  }
  const float bv = bias[col];

  // stage: thread handles chunks tid and tid+512 of 1024 (32 rows x 32 chunks)
  const int r0c = tid >> 5, r1c = (tid + 512) >> 5;
  const int cc = tid & 31;                  // (tid+512)&31 == tid&31
  f32x4 sa[2][2];

  int t = blockIdx.x;
  // prologue load of tile t
  {
    const float* xp0 = X + ((size_t)t * 32 + r0c) * K + cc * 8;
    const float* xp1 = X + ((size_t)t * 32 + r1c) * K + cc * 8;
    sa[0][0] = *(const f32x4*)xp0; sa[0][1] = *(const f32x4*)(xp0 + 4);
    sa[1][0] = *(const f32x4*)xp1; sa[1][1] = *(const f32x4*)(xp1 + 4);
  }
  while (t < ntiles) {
    // split + LDS write of tile t
    {
      const int slot0 = r0c * CPR + (cc ^ (r0c & 7));
      const int slot1 = r1c * CPR + (cc ^ (r1c & 7));
      bf16x8 h, l;
      split8(sa[0][0], sa[0][1], h, l);
      *(bf16x8*)&hi_p[slot0 * 8] = h;
      *(bf16x8*)&lo_p[slot0 * 8] = l;
      split8(sa[1][0], sa[1][1], h, l);
      *(bf16x8*)&hi_p[slot1 * 8] = h;
      *(bf16x8*)&lo_p[slot1 * 8] = l;
    }
    __syncthreads();
    // issue next-tile loads (land in regs; in flight during compute)
    const int tn = t + (int)gridDim.x;
    {
      const int tl = (tn < ntiles) ? tn : (int)blockIdx.x;  // clamp: safe addr
      const float* xp0 = X + ((size_t)tl * 32 + r0c) * K + cc * 8;
      const float* xp1 = X + ((size_t)tl * 32 + r1c) * K + cc * 8;
      sa[0][0] = *(const f32x4*)xp0; sa[0][1] = *(const f32x4*)(xp0 + 4);
      sa[1][0] = *(const f32x4*)xp1; sa[1][1] = *(const f32x4*)(xp1 + 4);
    }
    // compute tile t
    f32x4 acc[RT];
#pragma unroll
    for (int rt = 0; rt < RT; ++rt) acc[rt] = f32x4{0.f, 0.f, 0.f, 0.f};
#pragma unroll
    for (int kt = 0; kt < KT; ++kt) {
      bf16x8 ahi[RT], alo[RT];
#pragma unroll
      for (int rt = 0; rt < RT; ++rt) {
        const int lr = rt * 16 + lrow;
        const int off = (lr * CPR + ((kt * 4 + loct) ^ (lr & 7))) * 8;
        ahi[rt] = *(const bf16x8*)&hi_p[off];
        alo[rt] = *(const bf16x8*)&lo_p[off];
      }
#pragma unroll
      for (int rt = 0; rt < RT; ++rt) {
        acc[rt] = __builtin_amdgcn_mfma_f32_16x16x32_bf16(ahi[rt], bhi[kt], acc[rt], 0, 0, 0);
        acc[rt] = __builtin_amdgcn_mfma_f32_16x16x32_bf16(ahi[rt], blo[kt], acc[rt], 0, 0, 0);
        acc[rt] = __builtin_amdgcn_mfma_f32_16x16x32_bf16(alo[rt], bhi[kt], acc[rt], 0, 0, 0);
      }
    }
    // epilogue: relu(acc + b) -> pk store
    const int rbase = t * 32;
#pragma unroll
    for (int rt = 0; rt < RT; ++rt)
#pragma unroll
      for (int r = 0; r < 4; ++r) {
        const float v = fmaxf(acc[rt][r] + bv, 0.f);
        Ypk[(size_t)(rbase + rt * 16 + loct * 4 + r) * 128 + col] = packsplit(v);
      }
    t = tn;
    __syncthreads();
  }
}

// ---------------- MFMA GEMM (K=128): pk in, pk(+fp8)/f32 out ---------------
template <int K, int WAVES, bool IN_F32, bool OUT_PK, bool OUT_FP8, bool HAS_BIAS, bool RELU>
__global__ __launch_bounds__(WAVES * 64) void gemm_mfma(
    const void* __restrict__ Xv, const short* __restrict__ Whi,
    const short* __restrict__ Wlo, const float* __restrict__ bias,
    void* __restrict__ Yv, unsigned char* __restrict__ Yf8) {
  constexpr int KT = K / 32;
  constexpr int CT = 8 / WAVES;
  constexpr int RT = 2;
  constexpr int CPR = K / 8;
  __shared__ short hi_p[32 * K];
  __shared__ short lo_p[32 * K];
  const int tid = threadIdx.x;
  const int lane = tid & 63;
  const int wave = tid >> 6;
  const int lrow = lane & 15;
  const int loct = lane >> 4;
  const int r0 = blockIdx.x * 32;

  bf16x8 bhi[CT][KT], blo[CT][KT];
#pragma unroll
  for (int ct = 0; ct < CT; ++ct) {
    const int col = (wave * CT + ct) * 16 + lrow;
#pragma unroll
    for (int kt = 0; kt < KT; ++kt) {
      const int off = col * K + kt * 32 + loct * 8;
      bhi[ct][kt] = *(const bf16x8*)&Whi[off];
      blo[ct][kt] = *(const bf16x8*)&Wlo[off];
    }
  }
  float bv[CT];
  if constexpr (HAS_BIAS) {
#pragma unroll
    for (int ct = 0; ct < CT; ++ct) bv[ct] = bias[(wave * CT + ct) * 16 + lrow];
  }

#pragma unroll
  for (int s = tid; s < 32 * CPR; s += WAVES * 64) {
    const int r = s / CPR, c = s % CPR;
    const int slot = r * CPR + (c ^ (r & 7));
    if constexpr (IN_F32) {
      const float* xp = (const float*)Xv + (size_t)(r0 + r) * K + c * 8;
      bf16x8 h, l;
      split8(*(const f32x4*)xp, *(const f32x4*)(xp + 4), h, l);
      *(bf16x8*)&hi_p[slot * 8] = h;
      *(bf16x8*)&lo_p[slot * 8] = l;
    } else {
      const unsigned* xp = (const unsigned*)Xv + (size_t)(r0 + r) * K + c * 8;
      const u32x4 a = *(const u32x4*)xp;
      const u32x4 b = *(const u32x4*)(xp + 4);
      u32x4 wh, wl;
      wh[0] = (a[1] & 0xFFFF0000u) | (a[0] >> 16);
      wh[1] = (a[3] & 0xFFFF0000u) | (a[2] >> 16);
      wh[2] = (b[1] & 0xFFFF0000u) | (b[0] >> 16);
      wh[3] = (b[3] & 0xFFFF0000u) | (b[2] >> 16);
      wl[0] = (a[1] << 16) | (a[0] & 0xFFFFu);
      wl[1] = (a[3] << 16) | (a[2] & 0xFFFFu);
      wl[2] = (b[1] << 16) | (b[0] & 0xFFFFu);
      wl[3] = (b[3] << 16) | (b[2] & 0xFFFFu);
      *(u32x4*)&hi_p[slot * 8] = wh;
      *(u32x4*)&lo_p[slot * 8] = wl;
    }
  }
  __syncthreads();

  f32x4 acc[RT][CT];
#pragma unroll
  for (int rt = 0; rt < RT; ++rt)
#pragma unroll
    for (int ct = 0; ct < CT; ++ct) acc[rt][ct] = f32x4{0.f, 0.f, 0.f, 0.f};

#pragma unroll
  for (int kt = 0; kt < KT; ++kt) {
    bf16x8 ahi[RT], alo[RT];
#pragma unroll
    for (int rt = 0; rt < RT; ++rt) {
      const int lr = rt * 16 + lrow;
      const int off = (lr * CPR + ((kt * 4 + loct) ^ (lr & 7))) * 8;
      ahi[rt] = *(const bf16x8*)&hi_p[off];
      alo[rt] = *(const bf16x8*)&lo_p[off];
    }
#pragma unroll
    for (int rt = 0; rt < RT; ++rt)
#pragma unroll
      for (int ct = 0; ct < CT; ++ct) {
        acc[rt][ct] = __builtin_amdgcn_mfma_f32_16x16x32_bf16(ahi[rt], bhi[ct][kt], acc[rt][ct], 0, 0, 0);
        acc[rt][ct] = __builtin_amdgcn_mfma_f32_16x16x32_bf16(ahi[rt], blo[ct][kt], acc[rt][ct], 0, 0, 0);
        acc[rt][ct] = __builtin_amdgcn_mfma_f32_16x16x32_bf16(alo[rt], bhi[ct][kt], acc[rt][ct], 0, 0, 0);
      }
  }

#pragma unroll
  for (int rt = 0; rt < RT; ++rt)
#pragma unroll
    for (int ct = 0; ct < CT; ++ct) {
      const int col = (wave * CT + ct) * 16 + lrow;
#pragma unroll
      for (int r = 0; r < 4; ++r) {
        float v = acc[rt][ct][r];
        if constexpr (HAS_BIAS) v += bv[ct];
        if constexpr (RELU) v = fmaxf(v, 0.f);
        const size_t idx = (size_t)(r0 + rt * 16 + loct * 4 + r) * 128 + col;
        if constexpr (OUT_PK) {
          ((unsigned*)Yv)[idx] = packsplit(v);
          if constexpr (OUT_FP8) Yf8[idx] = enc_e4m3(v);
        } else {
          ((float*)Yv)[idx] = v;
        }
      }
    }
}

// ---------------- gather-aggregate: one wave/node, fp8 neighbors -----------
// Hot loop per edge: cr load -> fp8 ushort load -> dec2 -> 1 mul + 2 fma.
template <bool RELU>
__global__ __launch_bounds__(256) void gather_kernel(const unsigned* __restrict__ xw,
                                                     const unsigned char* __restrict__ xf8,
                                                     const int* __restrict__ fill,
                                                     const unsigned* __restrict__ cv,
                                                     const float* __restrict__ dinv,
                                                     const float* __restrict__ bias,
                                                     unsigned* __restrict__ out, int N) {
  const int lane = threadIdx.x & 63;
  const int n = (blockIdx.x * blockDim.x + threadIdx.x) >> 6;
  if (n >= N) return;
  const int f = lane * 2;
  const float dn = dinv[n];
  const float dn2 = dn * dn;
  const uint2 xs = *(const uint2*)&xw[(size_t)n * 128 + f];
  float ax = dn2 * unpk(xs.x);
  float ay = dn2 * unpk(xs.y);
  const unsigned* row = cv + ((size_t)n << 6);
  const int c = min(fill[n], CAP);
  int e = 0;
  for (; e + 8 <= c; e += 8) {
    unsigned cr[8];
    unsigned short t[8];
#pragma unroll
    for (int j = 0; j < 8; ++j) cr[j] = row[e + j];
#pragma unroll
    for (int j = 0; j < 8; ++j)
      t[j] = *(const unsigned short*)&xf8[(size_t)(cr[j] & SRC_MASK) * 128 + f];
#pragma unroll
    for (int j = 0; j < 8; ++j) {
      const float vs = (float)(cr[j] >> 17) * DEC_SCALE;
      const f32x2 xy = dec2(t[j]);
      ax = fmaf(vs, xy.x, ax);
      ay = fmaf(vs, xy.y, ay);
    }
  }
  for (; e < c; ++e) {
    const unsigned cr = row[e];
    const float vs = (float)(cr >> 17) * DEC_SCALE;
    const f32x2 xy = dec2(*(const unsigned short*)&xf8[(size_t)(cr & SRC_MASK) * 128 + f]);
    ax = fmaf(vs, xy.x, ax);
    ay = fmaf(vs, xy.y, ay);
  }
  const float2 bb = *(const float2*)&bias[f];
  float o0 = ax + bb.x, o1 = ay + bb.y;
  if (RELU) { o0 = fmaxf(o0, 0.f); o1 = fmaxf(o1, 0.f); }
  uint2 res;
  res.x = packsplit(o0);
  res.y = packsplit(o1);
  *(uint2*)&out[(size_t)n * 128 + f] = res;
}

// ---------------------------------------------------------------------------
extern "C" void kernel_launch(void* const* d_in, const int* in_sizes, int n_in,
                              void* d_out, int out_size, void* d_ws, size_t ws_size,
                              hipStream_t stream) {
  const float* x     = (const float*)d_in[0];
  const int*   eidx  = (const int*)d_in[1];
  const float* ea    = (const float*)d_in[2];
  const float* W_in  = (const float*)d_in[3];
  const float* b_in  = (const float*)d_in[4];
  const float* W1    = (const float*)d_in[5];
  const float* b1    = (const float*)d_in[6];
  const float* W2    = (const float*)d_in[7];
  const float* b2    = (const float*)d_in[8];
  const float* W_out = (const float*)d_in[9];
  const float* b_out = (const float*)d_in[10];

  const int E = in_sizes[2] / 8;          // edge_attr [E,8]
  const int N = in_sizes[0] / 256;        // x [N,256]
  const int* srcp = eidx;                 // edge_index [2,E] row-major
  const int* dstp = eidx + E;
  const int NB = (N + BN - 1) / BN;       // buckets

  char* w = (char*)d_ws;
  size_t o = 0;
  auto take = [&](size_t bytes) -> void* {
    void* p = w + o;
    o += (bytes + 255) & ~(size_t)255;
    return p;
  };
  float* ew            = (float*)take((size_t)E * 4);
  float* partial       = (float*)take(1024 * 4);
  float* invnorm       = (float*)take(256);
  float* dinv          = (float*)take((size_t)N * 4);
  int*   fillg         = (int*)take((size_t)N * 4);
  short* whi           = (short*)take(81920 * 2);
  short* wlo           = (short*)take(81920 * 2);
  unsigned* cursors    = (unsigned*)take((size_t)NB * 16 * 4);  // 64B-padded
  unsigned long long* buckets = (unsigned long long*)take((size_t)NB * BCAP * 8);
  unsigned* cv         = (unsigned*)take((size_t)NB * BN * CAP * 4);
  unsigned* buf0       = (unsigned*)take((size_t)N * 128 * 4);
  unsigned* buf1       = (unsigned*)take((size_t)N * 128 * 4);
  unsigned char* buff8 = (unsigned char*)take((size_t)N * 128);
  float* outp          = (float*)d_out;

  const int ntiles = N / 32;              // N % 32 == 0

  // 1. edge weights + global L2 norm; pre-split weights
  ew_kernel<<<1024, 256, 0, stream>>>(ea, ew, partial, E);
  finish_norm_kernel<<<1, 256, 0, stream>>>(partial, invnorm);
  wsplit_kernel<<<320, 256, 0, stream>>>(W_in, W1, W2, W_out, whi, wlo);

  // 2. graph structure: bin -> per-bucket LDS build -> weight finalize
  cursor_init_kernel<<<(NB + 255) / 256, 256, 0, stream>>>(cursors, NB);
  bin_kernel<<<(E + CHUNK - 1) / CHUNK, 512, 0, stream>>>(srcp, dstp, ew, invnorm,
                                                          cursors, buckets, E, NB);
  build_kernel<<<NB, 256, 0, stream>>>(buckets, cursors, cv, dinv, fillg, N);
  val_finalize_kernel<<<(N * 16 + 255) / 256, 256, 0, stream>>>(cv, fillg, dinv, N);

  // 3. layer pipeline
  // h0 = relu(x @ W_in^T + b_in)                  -> buf0 (pk)   [pipelined]
  gemm_in_pipe<<<1024, 512, 0, stream>>>(x, whi, wlo, b_in, buf0, ntiles);
  // xw1 = h0 @ W1^T                               -> buf1 (pk) + buff8 (e4m3)
  gemm_mfma<128, 4, false, true, true, false, false><<<ntiles, 256, 0, stream>>>(
      buf0, whi + 32768, wlo + 32768, nullptr, buf1, buff8);
  // s1 = relu(agg(xw1) + b1)                      -> buf0 (pk)
  gather_kernel<true><<<(N * 64 + 255) / 256, 256, 0, stream>>>(buf1, buff8, fillg, cv, dinv, b1, buf0, N);
  // xw2 = s1 @ W2^T                               -> buf1 (pk) + buff8 (e4m3)
  gemm_mfma<128, 4, false, true, true, false, false><<<ntiles, 256, 0, stream>>>(
      buf0, whi + 49152, wlo + 49152, nullptr, buf1, buff8);
  // s2 = agg(xw2) + b2                            -> buf0 (pk)
  gather_kernel<false><<<(N * 64 + 255) / 256, 256, 0, stream>>>(buf1, buff8, fillg, cv, dinv, b2, buf0, N);
  // out = s2 @ W_out^T + b_out                    -> d_out (f32)
  gemm_mfma<128, 4, false, false, false, true, false><<<ntiles, 256, 0, stream>>>(
      buf0, whi + 65536, wlo + 65536, b_out, outp, nullptr);
}

// Round 12
// 338.890 us; speedup vs baseline: 1.4040x; 1.1647x over previous
//
#include <hip/hip_runtime.h>
#include <hip/hip_bf16.h>
#include <math.h>

// ---------------------------------------------------------------------------
// GNNReranker: 4-layer GCN on MI355X.
// Self-loop dominates the normalized adjacency (deg ~= 1.01):
//  - self term from pk (hi/lo bf16 pair, ~f32) stream,
//  - neighbor terms gathered from an fp8-e4m3 plane (1 B/feature).
// Edge weights FULLY pre-finalized into cv (w15 = dinv_s*dinv_d*ewn * 2^24);
// cv rows are zero-padded to CAP so the gather runs FULL 8-edge groups with
// no serial tail (padded slots have w15=0). GEMMs: bf16 MFMA, 3-product
// split accumulation; ALL pipelined persistent-block kernels (register-
// staged next-tile loads issued before the MFMA phase). Weights pre-split
// once into bf16 hi/lo planes. Graph build: two-phase binning.
// ---------------------------------------------------------------------------

#define CAP 64                 // padded CSR row capacity (mean deg 16)
#define BN 256                 // nodes per bucket
#define BCAP 5120              // bucket edge capacity (mean 4096, +16 sd)
#define CHUNK 4096             // edges per bin block
#define SRC_MASK 0x1FFFFu
#define Q_SCALE 16777216.0f    // 2^24
#define Q_INV   5.9604644775390625e-8f   // 2^-24

typedef __attribute__((ext_vector_type(8))) short bf16x8;
typedef __attribute__((ext_vector_type(2))) float f32x2;
typedef __attribute__((ext_vector_type(4))) float f32x4;
typedef __attribute__((ext_vector_type(4))) unsigned int u32x4;

#if __has_builtin(__builtin_amdgcn_cvt_pk_f32_fp8)
#define DEC_SCALE 5.9604644775390625e-8f   // 2^-24
__device__ __forceinline__ f32x2 dec2(unsigned short t) {
  return __builtin_amdgcn_cvt_pk_f32_fp8((int)(unsigned)t, false);
}
#else
#define DEC_SCALE 7.922816251426434e28f    // 2^96 = 2^-24 * 2^120
__device__ __forceinline__ f32x2 dec2(unsigned short t) {
  f32x2 r;
  r.x = __builtin_bit_cast(float, (((unsigned)t & 0x80u) << 24) | (((unsigned)t & 0x7Fu) << 20));
  r.y = __builtin_bit_cast(float, (((unsigned)t & 0x8000u) << 16) | (((unsigned)t & 0x7F00u) << 12));
  return r;
}
#endif

__device__ __forceinline__ unsigned rne_bf16(float f) {
  const unsigned u = __builtin_bit_cast(unsigned, f);
  return (u + 0x7FFFu + ((u >> 16) & 1u)) >> 16;
}
__device__ __forceinline__ unsigned packsplit(float f) {
  const unsigned hb = rne_bf16(f);
  const float hf = __builtin_bit_cast(float, hb << 16);
  const unsigned lb = rne_bf16(f - hf);
  return (hb << 16) | (lb & 0xFFFFu);
}
__device__ __forceinline__ float unpk(unsigned p) {
  return __builtin_bit_cast(float, p & 0xFFFF0000u) +
         __builtin_bit_cast(float, p << 16);
}
__device__ __forceinline__ void split8(const f32x4 a, const f32x4 b,
                                       bf16x8& hi, bf16x8& lo) {
#pragma unroll
  for (int i = 0; i < 8; ++i) {
    const float f = (i < 4) ? a[i] : b[i - 4];
    const unsigned hb = rne_bf16(f);
    hi[i] = (short)hb;
    const float hf = __builtin_bit_cast(float, hb << 16);
    lo[i] = (short)rne_bf16(f - hf);
  }
}
// f32 -> OCP e4m3 byte (RNE; clamped to max finite, never NaN)
__device__ __forceinline__ unsigned char enc_e4m3(float v) {
  const float a = v * 0x1p-120f;
  unsigned bits = __builtin_bit_cast(unsigned, a);
  const unsigned sgn = (bits >> 24) & 0x80u;
  bits &= 0x7FFFFFFFu;
  unsigned u7 = (bits + 0x7FFFFu + ((bits >> 20) & 1u)) >> 20;
  if (u7 > 0x7Eu) u7 = 0x7Eu;
  return (unsigned char)(sgn | u7);
}

// ---------------- edge weight + sum of squares (partial) -------------------
__global__ void ew_kernel(const float* __restrict__ ea, float* __restrict__ ew,
                          float* __restrict__ partial, int E) {
  __shared__ float red[256];
  const int tid = threadIdx.x;
  float ss = 0.f;
  const int stride = gridDim.x * blockDim.x;
  for (int e = blockIdx.x * blockDim.x + tid; e < E; e += stride) {
    const float4 a = *(const float4*)(ea + (size_t)e * 8);
    const float4 b = *(const float4*)(ea + (size_t)e * 8 + 4);
    const float s = ((a.x + a.y) + (a.z + a.w)) + ((b.x + b.y) + (b.z + b.w));
    ew[e] = s;
    ss = fmaf(s, s, ss);
  }
  red[tid] = ss;
  __syncthreads();
  for (int k = 128; k > 0; k >>= 1) {
    if (tid < k) red[tid] += red[tid + k];
    __syncthreads();
  }
  if (tid == 0) partial[blockIdx.x] = red[0];
}

__global__ void finish_norm_kernel(const float* __restrict__ partial,
                                   float* __restrict__ invnorm) {
  __shared__ float red[256];
  const int tid = threadIdx.x;
  float s = partial[tid] + partial[tid + 256] + partial[tid + 512] + partial[tid + 768];
  red[tid] = s;
  __syncthreads();
  for (int k = 128; k > 0; k >>= 1) {
    if (tid < k) red[tid] += red[tid + k];
    __syncthreads();
  }
  if (tid == 0) invnorm[0] = 1.0f / fmaxf(sqrtf(red[0]), 1e-12f);
}

// ---------------- pre-split ALL weights into bf16 hi/lo planes -------------
__global__ void wsplit_kernel(const float* __restrict__ W_in, const float* __restrict__ W1,
                              const float* __restrict__ W2, const float* __restrict__ W_out,
                              short* __restrict__ whi, short* __restrict__ wlo) {
  const int i = blockIdx.x * blockDim.x + threadIdx.x;
  if (i >= 81920) return;
  float f;
  if (i < 32768) f = W_in[i];
  else if (i < 49152) f = W1[i - 32768];
  else if (i < 65536) f = W2[i - 49152];
  else f = W_out[i - 65536];
  const unsigned hb = rne_bf16(f);
  whi[i] = (short)hb;
  wlo[i] = (short)rne_bf16(f - __builtin_bit_cast(float, hb << 16));
}

// ---------------- cursor init: one padded slot (64 B) per bucket -----------
__global__ void cursor_init_kernel(unsigned* __restrict__ cursors, int NB) {
  const int i = blockIdx.x * blockDim.x + threadIdx.x;
  if (i < NB) cursors[i * 16] = (unsigned)i * BCAP;
}

// ---------------- phase 1: bin edges by dst bucket -------------------------
__global__ __launch_bounds__(512) void bin_kernel(
    const int* __restrict__ src, const int* __restrict__ dst,
    const float* __restrict__ ew, const float* __restrict__ invnorm,
    unsigned* __restrict__ cursors, unsigned long long* __restrict__ buckets,
    int E, int NB) {
  __shared__ unsigned long long recs[CHUNK];   // 32 KB
  __shared__ unsigned hist[512];
  __shared__ unsigned base[512];
  const int tid = threadIdx.x;
  const int e0 = blockIdx.x * CHUNK;
  const int n = min(CHUNK, E - e0);
  for (int i = tid; i < NB; i += 512) hist[i] = 0;
  __syncthreads();
  const float inv = invnorm[0];
  for (int i = tid; i < n; i += 512) {
    const int s = src[e0 + i];
    const int d = dst[e0 + i];
    const float w = ew[e0 + i] * inv;
    const unsigned q = (unsigned)fminf(fmaf(w, Q_SCALE, 0.5f), 32767.0f);
    const unsigned long long r =
        ((unsigned long long)(((unsigned)d << 15) | q) << 32) | (unsigned)s;
    recs[i] = r;
    atomicAdd(&hist[d >> 8], 1u);
  }
  __syncthreads();
  for (int i = tid; i < NB; i += 512) {
    const unsigned c = hist[i];
    base[i] = c ? atomicAdd(&cursors[i * 16], c) : 0u;
    hist[i] = 0;
  }
  __syncthreads();
  for (int i = tid; i < n; i += 512) {
    const unsigned long long r = recs[i];
    const unsigned b = ((unsigned)(r >> 32) >> 15) >> 8;
    const unsigned pos = base[b] + atomicAdd(&hist[b], 1u);
    if (pos < (b + 1) * BCAP)
      __builtin_nontemporal_store(r, &buckets[pos]);
  }
}

// ---------------- phase 2: per-bucket LDS scatter + deg/dinv + stream ------
// cvl ZERO-INITIALIZED so padded slots carry (w15=0, src=0): the gather can
// read full 8-groups past c with zero contribution.
__global__ __launch_bounds__(256) void build_kernel(
    const unsigned long long* __restrict__ buckets,
    const unsigned* __restrict__ cursors,
    unsigned* __restrict__ cv, float* __restrict__ dinv,
    int* __restrict__ fillg, int N) {
  __shared__ unsigned cvl[BN * CAP];     // 64 KB
  __shared__ unsigned fl[BN];
  const int tid = threadIdx.x;
  const int b = blockIdx.x;
  const int n0 = b << 8;
  for (int i = tid; i < BN * CAP; i += 256) cvl[i] = 0;
  for (int i = tid; i < BN; i += 256) fl[i] = 0;
  __syncthreads();
  const unsigned start = (unsigned)b * BCAP;
  const int cnt = min((int)(cursors[b * 16] - start), BCAP);
  for (int i = tid; i < cnt; i += 256) {
    const unsigned long long r = buckets[start + i];
    const unsigned hi = (unsigned)(r >> 32);
    const unsigned dlo = (hi >> 15) & (BN - 1);
    const unsigned q = hi & 0x7FFFu;
    const unsigned p = atomicAdd(&fl[dlo], 1u);
    if (p < CAP) cvl[(dlo << 6) + p] = (q << 17) | (unsigned)(r & 0xFFFFFFFFu);
  }
  __syncthreads();
  if (n0 + tid < N) {
    const int c = min((int)fl[tid], CAP);
    unsigned qs = 0;
    for (int i = 0; i < c; ++i) qs += cvl[(tid << 6) + i] >> 17;
    dinv[n0 + tid] = rsqrtf(fmaf((float)qs, Q_INV, 1.0f));  // deg >= 1
    fillg[n0 + tid] = c;
  }
  const u32x4* s = (const u32x4*)cvl;
  u32x4* g = (u32x4*)(cv + ((size_t)b << 14));
  for (int i = tid; i < BN * CAP / 4; i += 256)
    __builtin_nontemporal_store(s[i], &g[i]);
}

// ---------------- finalize edge weights: q15 -> w15 ------------------------
__global__ void val_finalize_kernel(unsigned* __restrict__ cv, const int* __restrict__ fillg,
                                    const float* __restrict__ dinv, int N) {
  const int i = blockIdx.x * blockDim.x + threadIdx.x;
  if (i >= N * (CAP / 4)) return;
  const int n = i >> 4;
  const int slot0 = (i & 15) * 4;
  const int c = fillg[n];
  if (slot0 >= c) return;
  const float dn = dinv[n];
  u32x4 q = *(u32x4*)&cv[((size_t)n << 6) + slot0];
#pragma unroll
  for (int j = 0; j < 4; ++j) {
    if (slot0 + j < c) {
      const unsigned s = q[j] & SRC_MASK;
      const float wv = dinv[s] * dn * ((float)(q[j] >> 17) * Q_INV);
      const unsigned w15 = (unsigned)fminf(fmaf(wv, Q_SCALE, 0.5f), 32767.0f);
      q[j] = (w15 << 17) | s;
    }
  }
  *(u32x4*)&cv[((size_t)n << 6) + slot0] = q;
}

// ---------------- pipelined input GEMM: f32 x[N,256] -> relu(x@W^T+b) pk ---
__global__ __launch_bounds__(512, 4) void gemm_in_pipe(
    const float* __restrict__ X, const short* __restrict__ Whi,
    const short* __restrict__ Wlo, const float* __restrict__ bias,
    unsigned* __restrict__ Ypk, int ntiles) {
  constexpr int K = 256, KT = 8, RT = 2, CPR = 32;
  __shared__ short hi_p[32 * K];   // 16 KB
  __shared__ short lo_p[32 * K];   // 16 KB
  const int tid = threadIdx.x;
  const int lane = tid & 63, wave = tid >> 6;
  const int lrow = lane & 15, loct = lane >> 4;

  bf16x8 bhi[KT], blo[KT];
  const int col = wave * 16 + lrow;
#pragma unroll
  for (int kt = 0; kt < KT; ++kt) {
    const int off = col * K + kt * 32 + loct * 8;
    bhi[kt] = *(const bf16x8*)&Whi[off];
    blo[kt] = *(const bf16x8*)&Wlo[off];
  }
  const float bv = bias[col];

  const int r0c = tid >> 5, r1c = (tid + 512) >> 5;
  const int cc = tid & 31;
  f32x4 sa[2][2];

  int t = blockIdx.x;
  {
    const float* xp0 = X + ((size_t)t * 32 + r0c) * K + cc * 8;
    const float* xp1 = X + ((size_t)t * 32 + r1c) * K + cc * 8;
    sa[0][0] = *(const f32x4*)xp0; sa[0][1] = *(const f32x4*)(xp0 + 4);
    sa[1][0] = *(const f32x4*)xp1; sa[1][1] = *(const f32x4*)(xp1 + 4);
  }
  while (t < ntiles) {
    {
      const int slot0 = r0c * CPR + (cc ^ (r0c & 7));
      const int slot1 = r1c * CPR + (cc ^ (r1c & 7));
      bf16x8 h, l;
      split8(sa[0][0], sa[0][1], h, l);
      *(bf16x8*)&hi_p[slot0 * 8] = h;
      *(bf16x8*)&lo_p[slot0 * 8] = l;
      split8(sa[1][0], sa[1][1], h, l);
      *(bf16x8*)&hi_p[slot1 * 8] = h;
      *(bf16x8*)&lo_p[slot1 * 8] = l;
    }
    __syncthreads();
    const int tn = t + (int)gridDim.x;
    {
      const int tl = (tn < ntiles) ? tn : (int)blockIdx.x;
      const float* xp0 = X + ((size_t)tl * 32 + r0c) * K + cc * 8;
      const float* xp1 = X + ((size_t)tl * 32 + r1c) * K + cc * 8;
      sa[0][0] = *(const f32x4*)xp0; sa[0][1] = *(const f32x4*)(xp0 + 4);
      sa[1][0] = *(const f32x4*)xp1; sa[1][1] = *(const f32x4*)(xp1 + 4);
    }
    f32x4 acc[RT];
#pragma unroll
    for (int rt = 0; rt < RT; ++rt) acc[rt] = f32x4{0.f, 0.f, 0.f, 0.f};
#pragma unroll
    for (int kt = 0; kt < KT; ++kt) {
      bf16x8 ahi[RT], alo[RT];
#pragma unroll
      for (int rt = 0; rt < RT; ++rt) {
        const int lr = rt * 16 + lrow;
        const int off = (lr * CPR + ((kt * 4 + loct) ^ (lr & 7))) * 8;
        ahi[rt] = *(const bf16x8*)&hi_p[off];
        alo[rt] = *(const bf16x8*)&lo_p[off];
      }
#pragma unroll
      for (int rt = 0; rt < RT; ++rt) {
        acc[rt] = __builtin_amdgcn_mfma_f32_16x16x32_bf16(ahi[rt], bhi[kt], acc[rt], 0, 0, 0);
        acc[rt] = __builtin_amdgcn_mfma_f32_16x16x32_bf16(ahi[rt], blo[kt], acc[rt], 0, 0, 0);
        acc[rt] = __builtin_amdgcn_mfma_f32_16x16x32_bf16(alo[rt], bhi[kt], acc[rt], 0, 0, 0);
      }
    }
    const int rbase = t * 32;
#pragma unroll
    for (int rt = 0; rt < RT; ++rt)
#pragma unroll
      for (int r = 0; r < 4; ++r) {
        const float v = fmaxf(acc[rt][r] + bv, 0.f);
        Ypk[(size_t)(rbase + rt * 16 + loct * 4 + r) * 128 + col] = packsplit(v);
      }
    t = tn;
    __syncthreads();
  }
}

// ---------------- pipelined K=128 GEMM: pk in -> pk(+fp8) or f32 out -------
// Persistent blocks, register-staged next-tile prefetch, 16 KB LDS.
template <bool OUT_FP8, bool OUT_F32, bool HAS_BIAS, bool RELU>
__global__ __launch_bounds__(256, 4) void gemm_pk_pipe(
    const unsigned* __restrict__ Xpk, const short* __restrict__ Whi,
    const short* __restrict__ Wlo, const float* __restrict__ bias,
    unsigned* __restrict__ Ypk, unsigned char* __restrict__ Yf8,
    float* __restrict__ Yf32, int ntiles) {
  constexpr int K = 128, KT = 4, CT = 2, RT = 2, CPR = 16;
  __shared__ short hi_p[32 * K];   // 8 KB
  __shared__ short lo_p[32 * K];   // 8 KB
  const int tid = threadIdx.x;
  const int lane = tid & 63, wave = tid >> 6;
  const int lrow = lane & 15, loct = lane >> 4;

  bf16x8 bhi[CT][KT], blo[CT][KT];
#pragma unroll
  for (int ct = 0; ct < CT; ++ct) {
    const int col = (wave * CT + ct) * 16 + lrow;
#pragma unroll
    for (int kt = 0; kt < KT; ++kt) {
      const int off = col * K + kt * 32 + loct * 8;
      bhi[ct][kt] = *(const bf16x8*)&Whi[off];
      blo[ct][kt] = *(const bf16x8*)&Wlo[off];
    }
  }
  float bv[CT];
  if constexpr (HAS_BIAS) {
#pragma unroll
    for (int ct = 0; ct < CT; ++ct) bv[ct] = bias[(wave * CT + ct) * 16 + lrow];
  }

  // staging: 32 rows x 16 chunks (8 u32 = 32 B each); thread owns chunks
  // tid and tid+256.
  const int r0c = tid >> 4, r1c = (tid + 256) >> 4;
  const int cc = tid & 15;
  u32x4 sa[2][2];

  int t = blockIdx.x;
  {
    const unsigned* xp0 = Xpk + ((size_t)t * 32 + r0c) * K + cc * 8;
    const unsigned* xp1 = Xpk + ((size_t)t * 32 + r1c) * K + cc * 8;
    sa[0][0] = *(const u32x4*)xp0; sa[0][1] = *(const u32x4*)(xp0 + 4);
    sa[1][0] = *(const u32x4*)xp1; sa[1][1] = *(const u32x4*)(xp1 + 4);
  }
  while (t < ntiles) {
    // unpack pk -> hi/lo planes, swizzled
#pragma unroll
    for (int p = 0; p < 2; ++p) {
      const int r = p ? r1c : r0c;
      const int slot = r * CPR + (cc ^ (r & 7));
      const u32x4 a = sa[p][0], b = sa[p][1];
      u32x4 wh, wl;
      wh[0] = (a[1] & 0xFFFF0000u) | (a[0] >> 16);
      wh[1] = (a[3] & 0xFFFF0000u) | (a[2] >> 16);
      wh[2] = (b[1] & 0xFFFF0000u) | (b[0] >> 16);
      wh[3] = (b[3] & 0xFFFF0000u) | (b[2] >> 16);
      wl[0] = (a[1] << 16) | (a[0] & 0xFFFFu);
      wl[1] = (a[3] << 16) | (a[2] & 0xFFFFu);
      wl[2] = (b[1] << 16) | (b[0] & 0xFFFFu);
      wl[3] = (b[3] << 16) | (b[2] & 0xFFFFu);
      *(u32x4*)&hi_p[slot * 8] = wh;
      *(u32x4*)&lo_p[slot * 8] = wl;
    }
    __syncthreads();
    const int tn = t + (int)gridDim.x;
    {
      const int tl = (tn < ntiles) ? tn : (int)blockIdx.x;
      const unsigned* xp0 = Xpk + ((size_t)tl * 32 + r0c) * K + cc * 8;
      const unsigned* xp1 = Xpk + ((size_t)tl * 32 + r1c) * K + cc * 8;
      sa[0][0] = *(const u32x4*)xp0; sa[0][1] = *(const u32x4*)(xp0 + 4);
      sa[1][0] = *(const u32x4*)xp1; sa[1][1] = *(const u32x4*)(xp1 + 4);
    }
    f32x4 acc[RT][CT];
#pragma unroll
    for (int rt = 0; rt < RT; ++rt)
#pragma unroll
      for (int ct = 0; ct < CT; ++ct) acc[rt][ct] = f32x4{0.f, 0.f, 0.f, 0.f};
#pragma unroll
    for (int kt = 0; kt < KT; ++kt) {
      bf16x8 ahi[RT], alo[RT];
#pragma unroll
      for (int rt = 0; rt < RT; ++rt) {
        const int lr = rt * 16 + lrow;
        const int off = (lr * CPR + ((kt * 4 + loct) ^ (lr & 7))) * 8;
        ahi[rt] = *(const bf16x8*)&hi_p[off];
        alo[rt] = *(const bf16x8*)&lo_p[off];
      }
#pragma unroll
      for (int rt = 0; rt < RT; ++rt)
#pragma unroll
        for (int ct = 0; ct < CT; ++ct) {
          acc[rt][ct] = __builtin_amdgcn_mfma_f32_16x16x32_bf16(ahi[rt], bhi[ct][kt], acc[rt][ct], 0, 0, 0);
          acc[rt][ct] = __builtin_amdgcn_mfma_f32_16x16x32_bf16(ahi[rt], blo[ct][kt], acc[rt][ct], 0, 0, 0);
          acc[rt][ct] = __builtin_amdgcn_mfma_f32_16x16x32_bf16(alo[rt], bhi[ct][kt], acc[rt][ct], 0, 0, 0);
        }
    }
    const int rbase = t * 32;
#pragma unroll
    for (int rt = 0; rt < RT; ++rt)
#pragma unroll
      for (int ct = 0; ct < CT; ++ct) {
        const int col = (wave * CT + ct) * 16 + lrow;
#pragma unroll
        for (int r = 0; r < 4; ++r) {
          float v = acc[rt][ct][r];
          if constexpr (HAS_BIAS) v += bv[ct];
          if constexpr (RELU) v = fmaxf(v, 0.f);
          const size_t idx = (size_t)(rbase + rt * 16 + loct * 4 + r) * 128 + col;
          if constexpr (OUT_F32) {
            Yf32[idx] = v;
          } else {
            Ypk[idx] = packsplit(v);
            if constexpr (OUT_FP8) Yf8[idx] = enc_e4m3(v);
          }
        }
      }
    t = tn;
    __syncthreads();
  }
}

// ---------------- gather-aggregate: one wave/node, fp8 neighbors -----------
// Full 8-edge groups (padded slots have w15=0 -> zero contribution); cv row
// loaded as 2x u32x4 (broadcast) per group. No serial tail.
template <bool RELU>
__global__ __launch_bounds__(256) void gather_kernel(const unsigned* __restrict__ xw,
                                                     const unsigned char* __restrict__ xf8,
                                                     const int* __restrict__ fill,
                                                     const unsigned* __restrict__ cv,
                                                     const float* __restrict__ dinv,
                                                     const float* __restrict__ bias,
                                                     unsigned* __restrict__ out, int N) {
  const int lane = threadIdx.x & 63;
  const int n = (blockIdx.x * blockDim.x + threadIdx.x) >> 6;
  if (n >= N) return;
  const int f = lane * 2;
  const float dn = dinv[n];
  const float dn2 = dn * dn;
  const uint2 xs = *(const uint2*)&xw[(size_t)n * 128 + f];
  float ax = dn2 * unpk(xs.x);
  float ay = dn2 * unpk(xs.y);
  const unsigned* row = cv + ((size_t)n << 6);
  const int c = min(fill[n], CAP);
  for (int e = 0; e < c; e += 8) {
    const u32x4 ca = *(const u32x4*)&row[e];
    const u32x4 cb = *(const u32x4*)&row[e + 4];
    unsigned cr[8];
    cr[0] = ca[0]; cr[1] = ca[1]; cr[2] = ca[2]; cr[3] = ca[3];
    cr[4] = cb[0]; cr[5] = cb[1]; cr[6] = cb[2]; cr[7] = cb[3];
    unsigned short t[8];
#pragma unroll
    for (int j = 0; j < 8; ++j)
      t[j] = *(const unsigned short*)&xf8[(size_t)(cr[j] & SRC_MASK) * 128 + f];
#pragma unroll
    for (int j = 0; j < 8; ++j) {
      const float vs = (float)(cr[j] >> 17) * DEC_SCALE;
      const f32x2 xy = dec2(t[j]);
      ax = fmaf(vs, xy.x, ax);
      ay = fmaf(vs, xy.y, ay);
    }
  }
  const float2 bb = *(const float2*)&bias[f];
  float o0 = ax + bb.x, o1 = ay + bb.y;
  if (RELU) { o0 = fmaxf(o0, 0.f); o1 = fmaxf(o1, 0.f); }
  uint2 res;
  res.x = packsplit(o0);
  res.y = packsplit(o1);
  *(uint2*)&out[(size_t)n * 128 + f] = res;
}

// ---------------------------------------------------------------------------
extern "C" void kernel_launch(void* const* d_in, const int* in_sizes, int n_in,
                              void* d_out, int out_size, void* d_ws, size_t ws_size,
                              hipStream_t stream) {
  const float* x     = (const float*)d_in[0];
  const int*   eidx  = (const int*)d_in[1];
  const float* ea    = (const float*)d_in[2];
  const float* W_in  = (const float*)d_in[3];
  const float* b_in  = (const float*)d_in[4];
  const float* W1    = (const float*)d_in[5];
  const float* b1    = (const float*)d_in[6];
  const float* W2    = (const float*)d_in[7];
  const float* b2    = (const float*)d_in[8];
  const float* W_out = (const float*)d_in[9];
  const float* b_out = (const float*)d_in[10];

  const int E = in_sizes[2] / 8;          // edge_attr [E,8]
  const int N = in_sizes[0] / 256;        // x [N,256]
  const int* srcp = eidx;                 // edge_index [2,E] row-major
  const int* dstp = eidx + E;
  const int NB = (N + BN - 1) / BN;       // buckets

  char* w = (char*)d_ws;
  size_t o = 0;
  auto take = [&](size_t bytes) -> void* {
    void* p = w + o;
    o += (bytes + 255) & ~(size_t)255;
    return p;
  };
  float* ew            = (float*)take((size_t)E * 4);
  float* partial       = (float*)take(1024 * 4);
  float* invnorm       = (float*)take(256);
  float* dinv          = (float*)take((size_t)N * 4);
  int*   fillg         = (int*)take((size_t)N * 4);
  short* whi           = (short*)take(81920 * 2);
  short* wlo           = (short*)take(81920 * 2);
  unsigned* cursors    = (unsigned*)take((size_t)NB * 16 * 4);  // 64B-padded
  unsigned long long* buckets = (unsigned long long*)take((size_t)NB * BCAP * 8);
  unsigned* cv         = (unsigned*)take((size_t)NB * BN * CAP * 4);
  unsigned* buf0       = (unsigned*)take((size_t)N * 128 * 4);
  unsigned* buf1       = (unsigned*)take((size_t)N * 128 * 4);
  unsigned char* buff8 = (unsigned char*)take((size_t)N * 128);
  float* outp          = (float*)d_out;

  const int ntiles = N / 32;              // N % 32 == 0

  // 1. edge weights + global L2 norm; pre-split weights
  ew_kernel<<<1024, 256, 0, stream>>>(ea, ew, partial, E);
  finish_norm_kernel<<<1, 256, 0, stream>>>(partial, invnorm);
  wsplit_kernel<<<320, 256, 0, stream>>>(W_in, W1, W2, W_out, whi, wlo);

  // 2. graph structure: bin -> per-bucket LDS build -> weight finalize
  cursor_init_kernel<<<(NB + 255) / 256, 256, 0, stream>>>(cursors, NB);
  bin_kernel<<<(E + CHUNK - 1) / CHUNK, 512, 0, stream>>>(srcp, dstp, ew, invnorm,
                                                          cursors, buckets, E, NB);
  build_kernel<<<NB, 256, 0, stream>>>(buckets, cursors, cv, dinv, fillg, N);
  val_finalize_kernel<<<(N * 16 + 255) / 256, 256, 0, stream>>>(cv, fillg, dinv, N);

  // 3. layer pipeline (all GEMMs pipelined persistent-block)
  // h0 = relu(x @ W_in^T + b_in)                  -> buf0 (pk)
  gemm_in_pipe<<<1024, 512, 0, stream>>>(x, whi, wlo, b_in, buf0, ntiles);
  // xw1 = h0 @ W1^T                               -> buf1 (pk) + buff8 (e4m3)
  gemm_pk_pipe<true, false, false, false><<<1024, 256, 0, stream>>>(
      buf0, whi + 32768, wlo + 32768, nullptr, buf1, buff8, nullptr, ntiles);
  // s1 = relu(agg(xw1) + b1)                      -> buf0 (pk)
  gather_kernel<true><<<(N * 64 + 255) / 256, 256, 0, stream>>>(buf1, buff8, fillg, cv, dinv, b1, buf0, N);
  // xw2 = s1 @ W2^T                               -> buf1 (pk) + buff8 (e4m3)
  gemm_pk_pipe<true, false, false, false><<<1024, 256, 0, stream>>>(
      buf0, whi + 49152, wlo + 49152, nullptr, buf1, buff8, nullptr, ntiles);
  // s2 = agg(xw2) + b2                            -> buf0 (pk)
  gather_kernel<false><<<(N * 64 + 255) / 256, 256, 0, stream>>>(buf1, buff8, fillg, cv, dinv, b2, buf0, N);
  // out = s2 @ W_out^T + b_out                    -> d_out (f32)
  gemm_pk_pipe<false, true, true, false><<<1024, 256, 0, stream>>>(
      buf0, whi + 65536, wlo + 65536, b_out, nullptr, nullptr, outp, ntiles);
}

// Round 13
// 283.569 us; speedup vs baseline: 1.6779x; 1.1951x over previous
//
#include <hip/hip_runtime.h>
#include <hip/hip_bf16.h>
#include <math.h>

// ---------------------------------------------------------------------------
// GNNReranker: 4-layer GCN on MI355X.
// Self-loop dominates the normalized adjacency (deg ~= 1.01):
//  - self term from pk (hi/lo bf16 pair, ~f32) stream,
//  - neighbor terms gathered from an fp8-e4m3 plane (1 B/feature).
// Edge weights FULLY pre-finalized into cv (w15 = dinv_s*dinv_d*ewn * 2^24);
// cv rows zero-padded to CAP so the gather runs FULL 8-edge groups (no tail).
// GEMMs: bf16 MFMA, 3-product split accumulation, pipelined persistent
// blocks. Independent stages FUSED into one launch (role by blockIdx):
//   K1 = ew || wsplit;  K2 = norm || cursor_init;
//   K3 = bin || gemm_in;  K5 = val_finalize || gemm_pk1.
// Bucket record writes are plain stores (nt caused 6x write amplification).
// ---------------------------------------------------------------------------

#define CAP 64
#define BN 256
#define BCAP 5120
#define CHUNK 4096
#define SRC_MASK 0x1FFFFu
#define Q_SCALE 16777216.0f
#define Q_INV   5.9604644775390625e-8f
#define GSTRIDE 1024           // virtual grid for persistent gemm roles

typedef __attribute__((ext_vector_type(8))) short bf16x8;
typedef __attribute__((ext_vector_type(2))) float f32x2;
typedef __attribute__((ext_vector_type(4))) float f32x4;
typedef __attribute__((ext_vector_type(4))) unsigned int u32x4;

#if __has_builtin(__builtin_amdgcn_cvt_pk_f32_fp8)
#define DEC_SCALE 5.9604644775390625e-8f
__device__ __forceinline__ f32x2 dec2(unsigned short t) {
  return __builtin_amdgcn_cvt_pk_f32_fp8((int)(unsigned)t, false);
}
#else
#define DEC_SCALE 7.922816251426434e28f
__device__ __forceinline__ f32x2 dec2(unsigned short t) {
  f32x2 r;
  r.x = __builtin_bit_cast(float, (((unsigned)t & 0x80u) << 24) | (((unsigned)t & 0x7Fu) << 20));
  r.y = __builtin_bit_cast(float, (((unsigned)t & 0x8000u) << 16) | (((unsigned)t & 0x7F00u) << 12));
  return r;
}
#endif

__device__ __forceinline__ unsigned rne_bf16(float f) {
  const unsigned u = __builtin_bit_cast(unsigned, f);
  return (u + 0x7FFFu + ((u >> 16) & 1u)) >> 16;
}
__device__ __forceinline__ unsigned packsplit(float f) {
  const unsigned hb = rne_bf16(f);
  const float hf = __builtin_bit_cast(float, hb << 16);
  const unsigned lb = rne_bf16(f - hf);
  return (hb << 16) | (lb & 0xFFFFu);
}
__device__ __forceinline__ float unpk(unsigned p) {
  return __builtin_bit_cast(float, p & 0xFFFF0000u) +
         __builtin_bit_cast(float, p << 16);
}
__device__ __forceinline__ void split8(const f32x4 a, const f32x4 b,
                                       bf16x8& hi, bf16x8& lo) {
#pragma unroll
  for (int i = 0; i < 8; ++i) {
    const float f = (i < 4) ? a[i] : b[i - 4];
    const unsigned hb = rne_bf16(f);
    hi[i] = (short)hb;
    const float hf = __builtin_bit_cast(float, hb << 16);
    lo[i] = (short)rne_bf16(f - hf);
  }
}
__device__ __forceinline__ unsigned char enc_e4m3(float v) {
  const float a = v * 0x1p-120f;
  unsigned bits = __builtin_bit_cast(unsigned, a);
  const unsigned sgn = (bits >> 24) & 0x80u;
  bits &= 0x7FFFFFFFu;
  unsigned u7 = (bits + 0x7FFFFu + ((bits >> 20) & 1u)) >> 20;
  if (u7 > 0x7Eu) u7 = 0x7Eu;
  return (unsigned char)(sgn | u7);
}

// ---------------- K1: ew (blocks 0..1023) || wsplit (1024..1343) -----------
__global__ void ew_wsplit_kernel(const float* __restrict__ ea, float* __restrict__ ew,
                                 float* __restrict__ partial, int E,
                                 const float* __restrict__ W_in, const float* __restrict__ W1,
                                 const float* __restrict__ W2, const float* __restrict__ W_out,
                                 short* __restrict__ whi, short* __restrict__ wlo) {
  __shared__ float red[256];
  const int tid = threadIdx.x;
  if (blockIdx.x < 1024) {
    float ss = 0.f;
    const int stride = 1024 * 256;
    for (int e = blockIdx.x * 256 + tid; e < E; e += stride) {
      const float4 a = *(const float4*)(ea + (size_t)e * 8);
      const float4 b = *(const float4*)(ea + (size_t)e * 8 + 4);
      const float s = ((a.x + a.y) + (a.z + a.w)) + ((b.x + b.y) + (b.z + b.w));
      ew[e] = s;
      ss = fmaf(s, s, ss);
    }
    red[tid] = ss;
    __syncthreads();
    for (int k = 128; k > 0; k >>= 1) {
      if (tid < k) red[tid] += red[tid + k];
      __syncthreads();
    }
    if (tid == 0) partial[blockIdx.x] = red[0];
  } else {
    const int i = (blockIdx.x - 1024) * 256 + tid;
    if (i < 81920) {
      float f;
      if (i < 32768) f = W_in[i];
      else if (i < 49152) f = W1[i - 32768];
      else if (i < 65536) f = W2[i - 49152];
      else f = W_out[i - 65536];
      const unsigned hb = rne_bf16(f);
      whi[i] = (short)hb;
      wlo[i] = (short)rne_bf16(f - __builtin_bit_cast(float, hb << 16));
    }
  }
}

// ---------------- K2: finish_norm (block 0) || cursor_init (1..2) ----------
__global__ void norm_cursor_kernel(const float* __restrict__ partial,
                                   float* __restrict__ invnorm,
                                   unsigned* __restrict__ cursors, int NB) {
  __shared__ float red[256];
  const int tid = threadIdx.x;
  if (blockIdx.x == 0) {
    float s = partial[tid] + partial[tid + 256] + partial[tid + 512] + partial[tid + 768];
    red[tid] = s;
    __syncthreads();
    for (int k = 128; k > 0; k >>= 1) {
      if (tid < k) red[tid] += red[tid + k];
      __syncthreads();
    }
    if (tid == 0) invnorm[0] = 1.0f / fmaxf(sqrtf(red[0]), 1e-12f);
  } else {
    const int i = (blockIdx.x - 1) * 256 + tid;
    if (i < NB) cursors[i * 16] = (unsigned)i * BCAP;
  }
}

// ---------------- K3: bin (blocks 0..nbin-1) || gemm_in (persistent) -------
__global__ __launch_bounds__(512, 4) void bin_gemmin_kernel(
    const int* __restrict__ src, const int* __restrict__ dst,
    const float* __restrict__ ew, const float* __restrict__ invnorm,
    unsigned* __restrict__ cursors, unsigned long long* __restrict__ buckets,
    int E, int NB, int nbin,
    const float* __restrict__ X, const short* __restrict__ Whi,
    const short* __restrict__ Wlo, const float* __restrict__ bias,
    unsigned* __restrict__ Ypk, int ntiles) {
  __shared__ __align__(16) char smem[36864];
  const int tid = threadIdx.x;
  if ((int)blockIdx.x < nbin) {
    // ---- bin role ----
    unsigned long long* recs = (unsigned long long*)smem;     // 32 KB
    unsigned* hist = (unsigned*)(smem + 32768);               // 2 KB
    unsigned* base = (unsigned*)(smem + 34816);               // 2 KB
    const int e0 = blockIdx.x * CHUNK;
    const int n = min(CHUNK, E - e0);
    for (int i = tid; i < NB; i += 512) hist[i] = 0;
    __syncthreads();
    const float inv = invnorm[0];
    for (int i = tid; i < n; i += 512) {
      const int s = src[e0 + i];
      const int d = dst[e0 + i];
      const float w = ew[e0 + i] * inv;
      const unsigned q = (unsigned)fminf(fmaf(w, Q_SCALE, 0.5f), 32767.0f);
      recs[i] = ((unsigned long long)(((unsigned)d << 15) | q) << 32) | (unsigned)s;
      atomicAdd(&hist[d >> 8], 1u);
    }
    __syncthreads();
    for (int i = tid; i < NB; i += 512) {
      const unsigned c = hist[i];
      base[i] = c ? atomicAdd(&cursors[i * 16], c) : 0u;
      hist[i] = 0;
    }
    __syncthreads();
    for (int i = tid; i < n; i += 512) {
      const unsigned long long r = recs[i];
      const unsigned b = ((unsigned)(r >> 32) >> 15) >> 8;
      const unsigned pos = base[b] + atomicAdd(&hist[b], 1u);
      if (pos < (b + 1) * BCAP) buckets[pos] = r;   // plain store: L2 merges
    }
  } else {
    // ---- gemm_in role (persistent, virtual grid GSTRIDE) ----
    constexpr int K = 256, KT = 8, RT = 2, CPR = 32;
    short* hi_p = (short*)smem;            // 16 KB
    short* lo_p = (short*)(smem + 16384);  // 16 KB
    const int lane = tid & 63, wave = tid >> 6;
    const int lrow = lane & 15, loct = lane >> 4;

    bf16x8 bhi[KT], blo[KT];
    const int col = wave * 16 + lrow;
#pragma unroll
    for (int kt = 0; kt < KT; ++kt) {
      const int off = col * K + kt * 32 + loct * 8;
      bhi[kt] = *(const bf16x8*)&Whi[off];
      blo[kt] = *(const bf16x8*)&Wlo[off];
    }
    const float bv = bias[col];

    const int r0c = tid >> 5, r1c = (tid + 512) >> 5;
    const int cc = tid & 31;
    f32x4 sa[2][2];
    const int vb = (int)blockIdx.x - nbin;

    int t = vb;
    {
      const int tl = (t < ntiles) ? t : 0;
      const float* xp0 = X + ((size_t)tl * 32 + r0c) * K + cc * 8;
      const float* xp1 = X + ((size_t)tl * 32 + r1c) * K + cc * 8;
      sa[0][0] = *(const f32x4*)xp0; sa[0][1] = *(const f32x4*)(xp0 + 4);
      sa[1][0] = *(const f32x4*)xp1; sa[1][1] = *(const f32x4*)(xp1 + 4);
    }
    while (t < ntiles) {
      {
        const int slot0 = r0c * CPR + (cc ^ (r0c & 7));
        const int slot1 = r1c * CPR + (cc ^ (r1c & 7));
        bf16x8 h, l;
        split8(sa[0][0], sa[0][1], h, l);
        *(bf16x8*)&hi_p[slot0 * 8] = h;
        *(bf16x8*)&lo_p[slot0 * 8] = l;
        split8(sa[1][0], sa[1][1], h, l);
        *(bf16x8*)&hi_p[slot1 * 8] = h;
        *(bf16x8*)&lo_p[slot1 * 8] = l;
      }
      __syncthreads();
      const int tn = t + GSTRIDE;
      {
        const int tl = (tn < ntiles) ? tn : 0;
        const float* xp0 = X + ((size_t)tl * 32 + r0c) * K + cc * 8;
        const float* xp1 = X + ((size_t)tl * 32 + r1c) * K + cc * 8;
        sa[0][0] = *(const f32x4*)xp0; sa[0][1] = *(const f32x4*)(xp0 + 4);
        sa[1][0] = *(const f32x4*)xp1; sa[1][1] = *(const f32x4*)(xp1 + 4);
      }
      f32x4 acc[RT];
#pragma unroll
      for (int rt = 0; rt < RT; ++rt) acc[rt] = f32x4{0.f, 0.f, 0.f, 0.f};
#pragma unroll
      for (int kt = 0; kt < KT; ++kt) {
        bf16x8 ahi[RT], alo[RT];
#pragma unroll
        for (int rt = 0; rt < RT; ++rt) {
          const int lr = rt * 16 + lrow;
          const int off = (lr * CPR + ((kt * 4 + loct) ^ (lr & 7))) * 8;
          ahi[rt] = *(const bf16x8*)&hi_p[off];
          alo[rt] = *(const bf16x8*)&lo_p[off];
        }
#pragma unroll
        for (int rt = 0; rt < RT; ++rt) {
          acc[rt] = __builtin_amdgcn_mfma_f32_16x16x32_bf16(ahi[rt], bhi[kt], acc[rt], 0, 0, 0);
          acc[rt] = __builtin_amdgcn_mfma_f32_16x16x32_bf16(ahi[rt], blo[kt], acc[rt], 0, 0, 0);
          acc[rt] = __builtin_amdgcn_mfma_f32_16x16x32_bf16(alo[rt], bhi[kt], acc[rt], 0, 0, 0);
        }
      }
      const int rbase = t * 32;
#pragma unroll
      for (int rt = 0; rt < RT; ++rt)
#pragma unroll
        for (int r = 0; r < 4; ++r) {
          const float v = fmaxf(acc[rt][r] + bv, 0.f);
          Ypk[(size_t)(rbase + rt * 16 + loct * 4 + r) * 128 + col] = packsplit(v);
        }
      t = tn;
      __syncthreads();
    }
  }
}

// ---------------- K4: per-bucket LDS scatter + deg/dinv + stream -----------
__global__ __launch_bounds__(256) void build_kernel(
    const unsigned long long* __restrict__ buckets,
    const unsigned* __restrict__ cursors,
    unsigned* __restrict__ cv, float* __restrict__ dinv,
    int* __restrict__ fillg, int N) {
  __shared__ unsigned cvl[BN * CAP];     // 64 KB
  __shared__ unsigned fl[BN];
  const int tid = threadIdx.x;
  const int b = blockIdx.x;
  const int n0 = b << 8;
  for (int i = tid; i < BN * CAP; i += 256) cvl[i] = 0;
  for (int i = tid; i < BN; i += 256) fl[i] = 0;
  __syncthreads();
  const unsigned start = (unsigned)b * BCAP;
  const int cnt = min((int)(cursors[b * 16] - start), BCAP);
  for (int i = tid; i < cnt; i += 256) {
    const unsigned long long r = buckets[start + i];
    const unsigned hi = (unsigned)(r >> 32);
    const unsigned dlo = (hi >> 15) & (BN - 1);
    const unsigned q = hi & 0x7FFFu;
    const unsigned p = atomicAdd(&fl[dlo], 1u);
    if (p < CAP) cvl[(dlo << 6) + p] = (q << 17) | (unsigned)(r & 0xFFFFFFFFu);
  }
  __syncthreads();
  if (n0 + tid < N) {
    const int c = min((int)fl[tid], CAP);
    unsigned qs = 0;
    for (int i = 0; i < c; ++i) qs += cvl[(tid << 6) + i] >> 17;
    dinv[n0 + tid] = rsqrtf(fmaf((float)qs, Q_INV, 1.0f));
    fillg[n0 + tid] = c;
  }
  const u32x4* s = (const u32x4*)cvl;
  u32x4* g = (u32x4*)(cv + ((size_t)b << 14));
  for (int i = tid; i < BN * CAP / 4; i += 256)
    __builtin_nontemporal_store(s[i], &g[i]);   // coalesced full lines: nt ok
}

// ---------------- shared gemm_pk body (persistent, explicit stride) --------
template <bool OUT_FP8, bool OUT_F32, bool HAS_BIAS, bool RELU>
__device__ __forceinline__ void gemm_pk_body(
    char* smem, int vb, int stride,
    const unsigned* __restrict__ Xpk, const short* __restrict__ Whi,
    const short* __restrict__ Wlo, const float* __restrict__ bias,
    unsigned* __restrict__ Ypk, unsigned char* __restrict__ Yf8,
    float* __restrict__ Yf32, int ntiles) {
  constexpr int K = 128, KT = 4, CT = 2, RT = 2, CPR = 16;
  short* hi_p = (short*)smem;            // 8 KB
  short* lo_p = (short*)(smem + 8192);   // 8 KB
  const int tid = threadIdx.x;
  const int lane = tid & 63, wave = tid >> 6;
  const int lrow = lane & 15, loct = lane >> 4;

  bf16x8 bhi[CT][KT], blo[CT][KT];
#pragma unroll
  for (int ct = 0; ct < CT; ++ct) {
    const int col = (wave * CT + ct) * 16 + lrow;
#pragma unroll
    for (int kt = 0; kt < KT; ++kt) {
      const int off = col * K + kt * 32 + loct * 8;
      bhi[ct][kt] = *(const bf16x8*)&Whi[off];
      blo[ct][kt] = *(const bf16x8*)&Wlo[off];
    }
  }
  float bv[CT];
  if constexpr (HAS_BIAS) {
#pragma unroll
    for (int ct = 0; ct < CT; ++ct) bv[ct] = bias[(wave * CT + ct) * 16 + lrow];
  }

  const int r0c = tid >> 4, r1c = (tid + 256) >> 4;
  const int cc = tid & 15;
  u32x4 sa[2][2];

  int t = vb;
  {
    const int tl = (t < ntiles) ? t : 0;
    const unsigned* xp0 = Xpk + ((size_t)tl * 32 + r0c) * K + cc * 8;
    const unsigned* xp1 = Xpk + ((size_t)tl * 32 + r1c) * K + cc * 8;
    sa[0][0] = *(const u32x4*)xp0; sa[0][1] = *(const u32x4*)(xp0 + 4);
    sa[1][0] = *(const u32x4*)xp1; sa[1][1] = *(const u32x4*)(xp1 + 4);
  }
  while (t < ntiles) {
#pragma unroll
    for (int p = 0; p < 2; ++p) {
      const int r = p ? r1c : r0c;
      const int slot = r * CPR + (cc ^ (r & 7));
      const u32x4 a = sa[p][0], b = sa[p][1];
      u32x4 wh, wl;
      wh[0] = (a[1] & 0xFFFF0000u) | (a[0] >> 16);
      wh[1] = (a[3] & 0xFFFF0000u) | (a[2] >> 16);
      wh[2] = (b[1] & 0xFFFF0000u) | (b[0] >> 16);
      wh[3] = (b[3] & 0xFFFF0000u) | (b[2] >> 16);
      wl[0] = (a[1] << 16) | (a[0] & 0xFFFFu);
      wl[1] = (a[3] << 16) | (a[2] & 0xFFFFu);
      wl[2] = (b[1] << 16) | (b[0] & 0xFFFFu);
      wl[3] = (b[3] << 16) | (b[2] & 0xFFFFu);
      *(u32x4*)&hi_p[slot * 8] = wh;
      *(u32x4*)&lo_p[slot * 8] = wl;
    }
    __syncthreads();
    const int tn = t + stride;
    {
      const int tl = (tn < ntiles) ? tn : 0;
      const unsigned* xp0 = Xpk + ((size_t)tl * 32 + r0c) * K + cc * 8;
      const unsigned* xp1 = Xpk + ((size_t)tl * 32 + r1c) * K + cc * 8;
      sa[0][0] = *(const u32x4*)xp0; sa[0][1] = *(const u32x4*)(xp0 + 4);
      sa[1][0] = *(const u32x4*)xp1; sa[1][1] = *(const u32x4*)(xp1 + 4);
    }
    f32x4 acc[RT][CT];
#pragma unroll
    for (int rt = 0; rt < RT; ++rt)
#pragma unroll
      for (int ct = 0; ct < CT; ++ct) acc[rt][ct] = f32x4{0.f, 0.f, 0.f, 0.f};
#pragma unroll
    for (int kt = 0; kt < KT; ++kt) {
      bf16x8 ahi[RT], alo[RT];
#pragma unroll
      for (int rt = 0; rt < RT; ++rt) {
        const int lr = rt * 16 + lrow;
        const int off = (lr * CPR + ((kt * 4 + loct) ^ (lr & 7))) * 8;
        ahi[rt] = *(const bf16x8*)&hi_p[off];
        alo[rt] = *(const bf16x8*)&lo_p[off];
      }
#pragma unroll
      for (int rt = 0; rt < RT; ++rt)
#pragma unroll
        for (int ct = 0; ct < CT; ++ct) {
          acc[rt][ct] = __builtin_amdgcn_mfma_f32_16x16x32_bf16(ahi[rt], bhi[ct][kt], acc[rt][ct], 0, 0, 0);
          acc[rt][ct] = __builtin_amdgcn_mfma_f32_16x16x32_bf16(ahi[rt], blo[ct][kt], acc[rt][ct], 0, 0, 0);
          acc[rt][ct] = __builtin_amdgcn_mfma_f32_16x16x32_bf16(alo[rt], bhi[ct][kt], acc[rt][ct], 0, 0, 0);
        }
    }
    const int rbase = t * 32;
#pragma unroll
    for (int rt = 0; rt < RT; ++rt)
#pragma unroll
      for (int ct = 0; ct < CT; ++ct) {
        const int col = (wave * CT + ct) * 16 + lrow;
#pragma unroll
        for (int r = 0; r < 4; ++r) {
          float v = acc[rt][ct][r];
          if constexpr (HAS_BIAS) v += bv[ct];
          if constexpr (RELU) v = fmaxf(v, 0.f);
          const size_t idx = (size_t)(rbase + rt * 16 + loct * 4 + r) * 128 + col;
          if constexpr (OUT_F32) {
            Yf32[idx] = v;
          } else {
            Ypk[idx] = packsplit(v);
            if constexpr (OUT_FP8) Yf8[idx] = enc_e4m3(v);
          }
        }
      }
    t = tn;
    __syncthreads();
  }
}

// ---------------- K5: val_finalize (blocks 0..511, strided) || gemm_pk1 ----
__global__ __launch_bounds__(256, 4) void valfin_gemmpk_kernel(
    unsigned* __restrict__ cv, const int* __restrict__ fillg,
    const float* __restrict__ dinv, int N,
    const unsigned* __restrict__ Xpk, const short* __restrict__ Whi,
    const short* __restrict__ Wlo, unsigned* __restrict__ Ypk,
    unsigned char* __restrict__ Yf8, int ntiles) {
  __shared__ __align__(16) char smem[16384];
  if (blockIdx.x < 512) {
    const int total = N * (CAP / 4);
    for (int i = blockIdx.x * 256 + threadIdx.x; i < total; i += 512 * 256) {
      const int n = i >> 4;
      const int slot0 = (i & 15) * 4;
      const int c = fillg[n];
      if (slot0 >= c) continue;
      const float dn = dinv[n];
      u32x4 q = *(u32x4*)&cv[((size_t)n << 6) + slot0];
#pragma unroll
      for (int j = 0; j < 4; ++j) {
        if (slot0 + j < c) {
          const unsigned s = q[j] & SRC_MASK;
          const float wv = dinv[s] * dn * ((float)(q[j] >> 17) * Q_INV);
          const unsigned w15 = (unsigned)fminf(fmaf(wv, Q_SCALE, 0.5f), 32767.0f);
          q[j] = (w15 << 17) | s;
        }
      }
      *(u32x4*)&cv[((size_t)n << 6) + slot0] = q;
    }
  } else {
    gemm_pk_body<true, false, false, false>(smem, (int)blockIdx.x - 512, GSTRIDE,
                                            Xpk, Whi, Wlo, nullptr, Ypk, Yf8,
                                            nullptr, ntiles);
  }
}

// ---------------- standalone pipelined K=128 GEMM --------------------------
template <bool OUT_FP8, bool OUT_F32, bool HAS_BIAS, bool RELU>
__global__ __launch_bounds__(256, 4) void gemm_pk_pipe(
    const unsigned* __restrict__ Xpk, const short* __restrict__ Whi,
    const short* __restrict__ Wlo, const float* __restrict__ bias,
    unsigned* __restrict__ Ypk, unsigned char* __restrict__ Yf8,
    float* __restrict__ Yf32, int ntiles) {
  __shared__ __align__(16) char smem[16384];
  gemm_pk_body<OUT_FP8, OUT_F32, HAS_BIAS, RELU>(smem, (int)blockIdx.x, GSTRIDE,
                                                 Xpk, Whi, Wlo, bias, Ypk, Yf8,
                                                 Yf32, ntiles);
}

// ---------------- gather-aggregate: one wave/node, fp8 neighbors -----------
template <bool RELU>
__global__ __launch_bounds__(256) void gather_kernel(const unsigned* __restrict__ xw,
                                                     const unsigned char* __restrict__ xf8,
                                                     const int* __restrict__ fill,
                                                     const unsigned* __restrict__ cv,
                                                     const float* __restrict__ dinv,
                                                     const float* __restrict__ bias,
                                                     unsigned* __restrict__ out, int N) {
  const int lane = threadIdx.x & 63;
  const int n = (blockIdx.x * blockDim.x + threadIdx.x) >> 6;
  if (n >= N) return;
  const int f = lane * 2;
  const float dn = dinv[n];
  const float dn2 = dn * dn;
  const uint2 xs = *(const uint2*)&xw[(size_t)n * 128 + f];
  float ax = dn2 * unpk(xs.x);
  float ay = dn2 * unpk(xs.y);
  const unsigned* row = cv + ((size_t)n << 6);
  const int c = min(fill[n], CAP);
  for (int e = 0; e < c; e += 8) {
    const u32x4 ca = *(const u32x4*)&row[e];
    const u32x4 cb = *(const u32x4*)&row[e + 4];
    unsigned cr[8];
    cr[0] = ca[0]; cr[1] = ca[1]; cr[2] = ca[2]; cr[3] = ca[3];
    cr[4] = cb[0]; cr[5] = cb[1]; cr[6] = cb[2]; cr[7] = cb[3];
    unsigned short t[8];
#pragma unroll
    for (int j = 0; j < 8; ++j)
      t[j] = *(const unsigned short*)&xf8[(size_t)(cr[j] & SRC_MASK) * 128 + f];
#pragma unroll
    for (int j = 0; j < 8; ++j) {
      const float vs = (float)(cr[j] >> 17) * DEC_SCALE;
      const f32x2 xy = dec2(t[j]);
      ax = fmaf(vs, xy.x, ax);
      ay = fmaf(vs, xy.y, ay);
    }
  }
  const float2 bb = *(const float2*)&bias[f];
  float o0 = ax + bb.x, o1 = ay + bb.y;
  if (RELU) { o0 = fmaxf(o0, 0.f); o1 = fmaxf(o1, 0.f); }
  uint2 res;
  res.x = packsplit(o0);
  res.y = packsplit(o1);
  *(uint2*)&out[(size_t)n * 128 + f] = res;
}

// ---------------------------------------------------------------------------
extern "C" void kernel_launch(void* const* d_in, const int* in_sizes, int n_in,
                              void* d_out, int out_size, void* d_ws, size_t ws_size,
                              hipStream_t stream) {
  const float* x     = (const float*)d_in[0];
  const int*   eidx  = (const int*)d_in[1];
  const float* ea    = (const float*)d_in[2];
  const float* W_in  = (const float*)d_in[3];
  const float* b_in  = (const float*)d_in[4];
  const float* W1    = (const float*)d_in[5];
  const float* b1    = (const float*)d_in[6];
  const float* W2    = (const float*)d_in[7];
  const float* b2    = (const float*)d_in[8];
  const float* W_out = (const float*)d_in[9];
  const float* b_out = (const float*)d_in[10];

  const int E = in_sizes[2] / 8;          // edge_attr [E,8]
  const int N = in_sizes[0] / 256;        // x [N,256]
  const int* srcp = eidx;                 // edge_index [2,E] row-major
  const int* dstp = eidx + E;
  const int NB = (N + BN - 1) / BN;       // buckets
  const int nbin = (E + CHUNK - 1) / CHUNK;

  char* w = (char*)d_ws;
  size_t o = 0;
  auto take = [&](size_t bytes) -> void* {
    void* p = w + o;
    o += (bytes + 255) & ~(size_t)255;
    return p;
  };
  float* ew            = (float*)take((size_t)E * 4);
  float* partial       = (float*)take(1024 * 4);
  float* invnorm       = (float*)take(256);
  float* dinv          = (float*)take((size_t)N * 4);
  int*   fillg         = (int*)take((size_t)N * 4);
  short* whi           = (short*)take(81920 * 2);
  short* wlo           = (short*)take(81920 * 2);
  unsigned* cursors    = (unsigned*)take((size_t)NB * 16 * 4);
  unsigned long long* buckets = (unsigned long long*)take((size_t)NB * BCAP * 8);
  unsigned* cv         = (unsigned*)take((size_t)NB * BN * CAP * 4);
  unsigned* buf0       = (unsigned*)take((size_t)N * 128 * 4);
  unsigned* buf1       = (unsigned*)take((size_t)N * 128 * 4);
  unsigned char* buff8 = (unsigned char*)take((size_t)N * 128);
  float* outp          = (float*)d_out;

  const int ntiles = N / 32;              // N % 32 == 0

  // K1: ew || wsplit
  ew_wsplit_kernel<<<1344, 256, 0, stream>>>(ea, ew, partial, E,
                                             W_in, W1, W2, W_out, whi, wlo);
  // K2: finish_norm || cursor_init
  norm_cursor_kernel<<<1 + (NB + 255) / 256, 256, 0, stream>>>(partial, invnorm, cursors, NB);
  // K3: bin || gemm_in  (h0 = relu(x@W_in^T+b_in) -> buf0)
  bin_gemmin_kernel<<<nbin + GSTRIDE, 512, 0, stream>>>(
      srcp, dstp, ew, invnorm, cursors, buckets, E, NB, nbin,
      x, whi, wlo, b_in, buf0, ntiles);
  // K4: build (cv zero-padded, fused deg/dinv)
  build_kernel<<<NB, 256, 0, stream>>>(buckets, cursors, cv, dinv, fillg, N);
  // K5: val_finalize || gemm_pk1  (xw1 = h0@W1^T -> buf1 + buff8)
  valfin_gemmpk_kernel<<<512 + GSTRIDE, 256, 0, stream>>>(
      cv, fillg, dinv, N, buf0, whi + 32768, wlo + 32768, buf1, buff8, ntiles);
  // K6: s1 = relu(agg(xw1) + b1) -> buf0
  gather_kernel<true><<<(N * 64 + 255) / 256, 256, 0, stream>>>(buf1, buff8, fillg, cv, dinv, b1, buf0, N);
  // K7: xw2 = s1@W2^T -> buf1 + buff8
  gemm_pk_pipe<true, false, false, false><<<GSTRIDE, 256, 0, stream>>>(
      buf0, whi + 49152, wlo + 49152, nullptr, buf1, buff8, nullptr, ntiles);
  // K8: s2 = agg(xw2) + b2 -> buf0
  gather_kernel<false><<<(N * 64 + 255) / 256, 256, 0, stream>>>(buf1, buff8, fillg, cv, dinv, b2, buf0, N);
  // K9: out = s2@W_out^T + b_out -> d_out (f32)
  gemm_pk_pipe<false, true, true, false><<<GSTRIDE, 256, 0, stream>>>(
      buf0, whi + 65536, wlo + 65536, b_out, nullptr, nullptr, outp, ntiles);
}